// Round 1
// baseline (967.670 us; speedup 1.0000x reference)
//
#include <hip/hip_runtime.h>
#include <hip/hip_bf16.h>
#include <math.h>

#define NBATCH 8
#define NBOX   20000
#define NCLS   80
#define NREL   51
#define MAXDET 300
#define CAP    2048
#define HISTB  4096
#define KTARGET 1024u
#define SCORE_THR 0.05f

// IoU > 0.5 test, bit-exact vs numpy (no FMA contraction, IEEE div).
// a = already-selected box (reference's `box`), b = candidate (reference's `boxes[n]`).
__device__ __forceinline__ bool iou_gt_half(float ax1, float ay1, float ax2, float ay2,
                                            float bx1, float by1, float bx2, float by2) {
  float ix1 = fmaxf(ax1, bx1);
  float iy1 = fmaxf(ay1, by1);
  float ix2 = fminf(ax2, bx2);
  float iy2 = fminf(ay2, by2);
  float dw = fmaxf(__fsub_rn(ix2, ix1), 0.0f);
  float dh = fmaxf(__fsub_rn(iy2, iy1), 0.0f);
  float inter = __fmul_rn(dw, dh);
  float aa = __fmul_rn(__fsub_rn(ax2, ax1), __fsub_rn(ay2, ay1));
  float ab = __fmul_rn(__fsub_rn(bx2, bx1), __fsub_rn(by2, by1));
  float uni = __fsub_rn(__fadd_rn(aa, ab), inter);
  if (!(uni > 0.0f)) return false;              // iou defined as 0 when union<=0
  return __fdiv_rn(inter, uni) > 0.5f;
}

// Kernel 1: per-(b,c) candidate selection (histogram top-K prefix), bitonic sort,
// greedy NMS walk. Writes per-class kept lists (descending score) to ws.
__global__ __launch_bounds__(256) void k_nms(const float* __restrict__ boxes,
                                             const float* __restrict__ cls,
                                             float* __restrict__ keptScore,
                                             int* __restrict__ keptN,
                                             int* __restrict__ keptCount,
                                             int* __restrict__ flags) {
  // Manual LDS aliasing: [0,40000) prefix16, later kept arrays; [40000,56384) hist, later keys.
  __shared__ __align__(16) char smem[57408];
  unsigned short* prefix = (unsigned short*)smem;                       // [NBOX]
  float* kbox = (float*)smem;                                           // [MAXDET*4] (alias, walk phase)
  int*   kn   = (int*)(smem + MAXDET * 16);                             // [MAXDET]
  float* ksc  = (float*)(smem + MAXDET * 16 + MAXDET * 4);              // [MAXDET]
  unsigned int* hist = (unsigned int*)(smem + 40000);                   // [HISTB]
  unsigned long long* keys = (unsigned long long*)(smem + 40000);       // [CAP] (alias, after threshold)
  unsigned int* psum = (unsigned int*)(smem + 40000 + HISTB * 4);       // [256]
  __shared__ unsigned int s_thr, s_sel, s_cnt;

  const int tid = threadIdx.x;
  const int bc = blockIdx.x;
  const int b = bc / NCLS, c = bc % NCLS;
  const float* col = cls + (size_t)b * NBOX * NCLS + c;

  for (int i = tid; i < HISTB; i += 256) hist[i] = 0u;
  __syncthreads();

  // Pass A: single global scan -> 16-bit prefix in LDS + bucket histogram.
  for (int n = tid; n < NBOX; n += 256) {
    float s = col[(size_t)n * NCLS];
    unsigned short pf = 0;
    if (s > SCORE_THR) {
      unsigned int bits = __float_as_uint(s);
      pf = (unsigned short)(bits >> 16);
      atomicAdd(&hist[bits >> 19], 1u);
    }
    prefix[n] = pf;
  }
  __syncthreads();

  // Suffix-sum over 4096 buckets (16 per thread + Hillis-Steele over 256 partials).
  unsigned int v = 0;
  const int hb = tid * (HISTB / 256);
#pragma unroll
  for (int t = 0; t < HISTB / 256; ++t) v += hist[hb + t];
  psum[tid] = v;
  __syncthreads();
  for (int off = 1; off < 256; off <<= 1) {
    unsigned int o = (tid + off < 256) ? psum[tid + off] : 0u;
    __syncthreads();
    v += o;
    psum[tid] = v;
    __syncthreads();
  }
  const unsigned int total = psum[0];

  if (total == 0u) {
    for (int r = tid; r < MAXDET; r += 256) {
      keptScore[bc * MAXDET + r] = -INFINITY;
      keptN[bc * MAXDET + r] = 0;
    }
    if (tid == 0) { keptCount[bc] = 0; flags[bc] = 0; }
    return;
  }

  const unsigned int target = total < KTARGET ? total : KTARGET;
  {
    unsigned int above = (tid < 255) ? psum[tid + 1] : 0u;
    if (v >= target && above < target) {   // exactly one thread qualifies
      unsigned int acc = 0;
      for (int u = hb + HISTB / 256 - 1; u >= hb; --u) {
        acc += hist[u];
        if (above + acc >= target) { s_thr = (unsigned int)u; s_sel = above + acc; break; }
      }
    }
  }
  if (tid == 0) s_cnt = 0u;
  __syncthreads();
  const unsigned int thrB = s_thr;
  const unsigned int selCount = s_sel;

  if (selCount > CAP) {  // pathological tie pile-up: defer to exact slow path
    for (int r = tid; r < MAXDET; r += 256) {
      keptScore[bc * MAXDET + r] = -INFINITY;
      keptN[bc * MAXDET + r] = 0;
    }
    if (tid == 0) { keptCount[bc] = 0; flags[bc] = 1; }
    return;
  }

  // Pass C: compact selected candidates (re-read exact score only for selected).
  for (int n = tid; n < NBOX; n += 256) {
    unsigned int pf = prefix[n];
    if (pf != 0u && (pf >> 3) >= thrB) {
      float s = col[(size_t)n * NCLS];
      unsigned int pos = atomicAdd(&s_cnt, 1u);
      keys[pos] = ((unsigned long long)__float_as_uint(s) << 32) | (~(unsigned int)n);
    }
  }
  __syncthreads();
  for (int i = (int)selCount + tid; i < CAP; i += 256) keys[i] = 0ull;
  __syncthreads();

  // Bitonic sort ascending over CAP u64 keys (top candidates end up at the tail).
  for (int k = 2; k <= CAP; k <<= 1) {
    for (int j = k >> 1; j > 0; j >>= 1) {
      for (int i = tid; i < CAP; i += 256) {
        int ixj = i ^ j;
        if (ixj > i) {
          unsigned long long a = keys[i], bk = keys[ixj];
          bool asc = ((i & k) == 0);
          if (asc ? (a > bk) : (a < bk)) { keys[i] = bk; keys[ixj] = a; }
        }
      }
      __syncthreads();
    }
  }

  // Greedy walk (wave 0 only): descending candidates, keep iff no kept box IoU>0.5.
  if (tid < 64) {
    const int lane = tid;
    int kept = 0;
    unsigned long long key = keys[CAP - 1];
    unsigned int curn = ~((unsigned int)key);
    float4 cb = ((const float4*)boxes)[(size_t)b * NBOX + curn];
    for (unsigned int j = 0; j < selCount && kept < MAXDET; ++j) {
      float s = __uint_as_float((unsigned int)(key >> 32));
      unsigned int n = curn;
      float4 cur = cb;
      // prefetch next candidate's box
      unsigned long long nkey = (j + 1 < selCount) ? keys[CAP - 2 - j] : 0ull;
      unsigned int nn2 = (j + 1 < selCount) ? ~((unsigned int)nkey) : 0u;
      cb = ((const float4*)boxes)[(size_t)b * NBOX + nn2];
      key = nkey;
      curn = nn2;
      bool sup = false;
      for (int i = lane; i < kept; i += 64) {
        float4 kb = ((const float4*)kbox)[i];
        if (iou_gt_half(kb.x, kb.y, kb.z, kb.w, cur.x, cur.y, cur.z, cur.w)) sup = true;
      }
      if (__ballot(sup) == 0ull) {
        if (lane < 4) kbox[kept * 4 + lane] = (lane == 0) ? cur.x : (lane == 1) ? cur.y : (lane == 2) ? cur.z : cur.w;
        if (lane == 0) { kn[kept] = (int)n; ksc[kept] = s; }
        __builtin_amdgcn_wave_barrier();
        ++kept;
      }
    }
    __builtin_amdgcn_wave_barrier();
    for (int r = lane; r < MAXDET; r += 64) {
      keptScore[bc * MAXDET + r] = (r < kept) ? ksc[r] : -INFINITY;
      keptN[bc * MAXDET + r] = (r < kept) ? kn[r] : 0;
    }
    if (lane == 0) {
      keptCount[bc] = kept;
      // Exactness flag: exhausted the sorted prefix with candidates remaining below it.
      flags[bc] = (kept < MAXDET && selCount < total) ? 1 : 0;
    }
  }
}

// Kernel 2: exact reference-style greedy NMS for flagged problems (expected: none fire).
__global__ __launch_bounds__(256) void k_slow(const float* __restrict__ boxes,
                                              const float* __restrict__ cls,
                                              float* __restrict__ keptScore,
                                              int* __restrict__ keptN,
                                              int* __restrict__ keptCount,
                                              const int* __restrict__ flags) {
  const int bc = blockIdx.x;
  if (flags[bc] == 0) return;
  const int tid = threadIdx.x;
  const int b = bc / NCLS, c = bc % NCLS;
  const float* col = cls + (size_t)b * NBOX * NCLS + c;
  __shared__ unsigned int sup[(NBOX + 31) / 32];
  __shared__ unsigned long long red[256];
  __shared__ float4 sbx;
  __shared__ int s_kept;
  for (int i = tid; i < (NBOX + 31) / 32; i += 256) sup[i] = 0u;
  if (tid == 0) s_kept = 0;
  __syncthreads();
  for (int it = 0; it < MAXDET; ++it) {
    unsigned long long best = 0ull;
    for (int n = tid; n < NBOX; n += 256) {
      if ((sup[n >> 5] >> (n & 31)) & 1u) continue;
      float s = col[(size_t)n * NCLS];
      if (s > SCORE_THR) {
        unsigned long long key = ((unsigned long long)__float_as_uint(s) << 32) | (~(unsigned int)n);
        if (key > best) best = key;
      }
    }
    red[tid] = best;
    __syncthreads();
    for (int off = 128; off > 0; off >>= 1) {
      if (tid < off) { unsigned long long o = red[tid + off]; if (o > red[tid]) red[tid] = o; }
      __syncthreads();
    }
    unsigned long long win = red[0];
    if (win == 0ull) break;
    unsigned int nw = ~((unsigned int)win);
    if (tid == 0) {
      int k = s_kept;
      keptScore[bc * MAXDET + k] = __uint_as_float((unsigned int)(win >> 32));
      keptN[bc * MAXDET + k] = (int)nw;
      s_kept = k + 1;
      sbx = ((const float4*)boxes)[(size_t)b * NBOX + nw];
    }
    __syncthreads();
    float4 bx = sbx;
    for (int n = tid; n < NBOX; n += 256) {
      float4 cb = ((const float4*)boxes)[(size_t)b * NBOX + n];
      if (iou_gt_half(bx.x, bx.y, bx.z, bx.w, cb.x, cb.y, cb.z, cb.w))
        atomicOr(&sup[n >> 5], 1u << (n & 31));
    }
    if (tid == 0) atomicOr(&sup[nw >> 5], 1u << (nw & 31));
    __syncthreads();
  }
  __syncthreads();
  const int kept = s_kept;
  for (int r = kept + tid; r < MAXDET; r += 256) {
    keptScore[bc * MAXDET + r] = -INFINITY;
    keptN[bc * MAXDET + r] = 0;
  }
  if (tid == 0) keptCount[bc] = kept;
}

// Kernel 3: per-batch 80-way sorted-list merge (= lax.top_k with flat-index tie-break)
// + output materialization (boxes, scores, labels, relationship argmax/max).
__global__ __launch_bounds__(256) void k_out(const float* __restrict__ boxes,
                                             const float* __restrict__ rel,
                                             const float* __restrict__ keptScore,
                                             const int* __restrict__ keptN,
                                             float* __restrict__ out) {
  __shared__ float sel_s[MAXDET];
  __shared__ int sel_c[MAXDET];
  __shared__ int sel_slot[MAXDET];
  const int tid = threadIdx.x;
  const int b = blockIdx.x;

  if (tid < 64) {
    const int lane = tid;
    const int c0 = lane;
    const int c1 = 64 + lane;
    const bool has1 = (c1 < NCLS);
    const float* ls0 = keptScore + ((size_t)b * NCLS + c0) * MAXDET;
    const float* ls1 = keptScore + ((size_t)b * NCLS + (has1 ? c1 : c0)) * MAXDET;
    int h0 = 0, h1 = 0;
    float v0 = ls0[0], w0 = ls0[1];
    float v1 = has1 ? ls1[0] : -INFINITY;
    float w1 = has1 ? ls1[1] : -INFINITY;
    for (int r = 0; r < MAXDET; ++r) {
      float bs; int bcl;
      if (has1 && v1 > v0) { bs = v1; bcl = c1; } else { bs = v0; bcl = c0; }
#pragma unroll
      for (int off = 32; off > 0; off >>= 1) {
        float os = __shfl_xor(bs, off);
        int oc = __shfl_xor(bcl, off);
        if (os > bs || (os == bs && oc < bcl)) { bs = os; bcl = oc; }
      }
      if (bcl == c0) {
        sel_s[r] = bs; sel_c[r] = bcl; sel_slot[r] = h0;
        ++h0; v0 = w0; w0 = (h0 + 1 < MAXDET) ? ls0[h0 + 1] : -INFINITY;
      } else if (has1 && bcl == c1) {
        sel_s[r] = bs; sel_c[r] = bcl; sel_slot[r] = h1;
        ++h1; v1 = w1; w1 = (h1 + 1 < MAXDET) ? ls1[h1 + 1] : -INFINITY;
      }
    }
  }
  __syncthreads();

  for (int r = tid; r < MAXDET; r += 256) {
    float s = sel_s[r];
    int c = sel_c[r];
    int slot = sel_slot[r];
    bool valid = (s != -INFINITY);
    int n = valid ? keptN[((size_t)b * NCLS + c) * MAXDET + slot] : 0;
    size_t nb = (size_t)b * NBOX + (unsigned int)n;
    float4 ob;
    if (valid) ob = ((const float4*)boxes)[nb];
    else { ob.x = ob.y = ob.z = ob.w = -1.0f; }
    ((float4*)out)[(size_t)b * MAXDET + r] = ob;
    const int sbase = NBATCH * MAXDET * 4;
    out[sbase + b * MAXDET + r] = valid ? s : -1.0f;
    out[sbase + NBATCH * MAXDET + b * MAXDET + r] = valid ? (float)c : -1.0f;
    float pm = -1.0f, pl = -1.0f;
    if (valid) {
      const float* rp = rel + nb * NREL;
      float best = rp[0]; int bi = 0;
      for (int p = 1; p < NREL; ++p) { float vv = rp[p]; if (vv > best) { best = vv; bi = p; } }
      pm = best; pl = (float)bi;
    }
    out[sbase + 2 * NBATCH * MAXDET + b * MAXDET + r] = pm;
    out[sbase + 3 * NBATCH * MAXDET + b * MAXDET + r] = pl;
  }
}

extern "C" void kernel_launch(void* const* d_in, const int* in_sizes, int n_in,
                              void* d_out, int out_size, void* d_ws, size_t ws_size,
                              hipStream_t stream) {
  (void)in_sizes; (void)n_in; (void)out_size; (void)ws_size;
  const float* boxes = (const float*)d_in[0];
  const float* cls   = (const float*)d_in[1];
  const float* rel   = (const float*)d_in[2];
  float* out = (float*)d_out;
  char* ws = (char*)d_ws;
  float* keptScore = (float*)ws;                                          // B*C*300 f32
  int*   keptN     = (int*)(ws + (size_t)NBATCH * NCLS * MAXDET * 4);     // B*C*300 i32
  int*   keptCount = (int*)(ws + (size_t)NBATCH * NCLS * MAXDET * 8);     // B*C i32
  int*   flags     = keptCount + NBATCH * NCLS;                           // B*C i32

  k_nms<<<NBATCH * NCLS, 256, 0, stream>>>(boxes, cls, keptScore, keptN, keptCount, flags);
  k_slow<<<NBATCH * NCLS, 256, 0, stream>>>(boxes, cls, keptScore, keptN, keptCount, flags);
  k_out<<<NBATCH, 256, 0, stream>>>(boxes, rel, keptScore, keptN, out);
}

// Round 2
// 456.452 us; speedup vs baseline: 2.1200x; 2.1200x over previous
//
#include <hip/hip_runtime.h>
#include <hip/hip_bf16.h>
#include <math.h>

#define NBATCH 8
#define NBOX   20000
#define NCLS   80
#define NREL   51
#define MAXDET 300
#define CAP    1024
#define TARGETK 1000u
#define HISTB  4096
#define SCORE_THR 0.05f

// IoU > 0.5, bit-exact vs numpy (no FMA contraction, IEEE div).
// a = already-selected (earlier) box, b = candidate — matches reference operand roles.
__device__ __forceinline__ bool iou_gt_half(float ax1, float ay1, float ax2, float ay2,
                                            float bx1, float by1, float bx2, float by2) {
  float ix1 = fmaxf(ax1, bx1);
  float iy1 = fmaxf(ay1, by1);
  float ix2 = fminf(ax2, bx2);
  float iy2 = fminf(ay2, by2);
  float dw = fmaxf(__fsub_rn(ix2, ix1), 0.0f);
  float dh = fmaxf(__fsub_rn(iy2, iy1), 0.0f);
  float inter = __fmul_rn(dw, dh);
  float aa = __fmul_rn(__fsub_rn(ax2, ax1), __fsub_rn(ay2, ay1));
  float ab = __fmul_rn(__fsub_rn(bx2, bx1), __fsub_rn(by2, by1));
  float uni = __fsub_rn(__fadd_rn(aa, ab), inter);
  if (!(uni > 0.0f)) return false;
  return __fdiv_rn(inter, uni) > 0.5f;
}

// Transpose cls (B,N,C) -> colS (B,C,N). LDS tile padded to stride 81 (odd -> conflict-free).
__global__ __launch_bounds__(256) void k_tr(const float* __restrict__ cls,
                                            float* __restrict__ colS) {
  __shared__ float tile[64 * 81];
  const int tid = threadIdx.x;
  const int b = blockIdx.y;
  const int n0 = blockIdx.x * 64;
  const int rows = (NBOX - n0) < 64 ? (NBOX - n0) : 64;
  const float* src = cls + ((size_t)b * NBOX + n0) * NCLS;
  for (int i = tid; i < rows * NCLS; i += 256) {
    int r = i / NCLS, c = i - r * NCLS;
    tile[r * 81 + c] = src[i];
  }
  __syncthreads();
  for (int i = tid; i < NCLS * 64; i += 256) {
    int c = i >> 6, nl = i & 63;
    if (nl < rows)
      colS[((size_t)b * NCLS + c) * NBOX + n0 + nl] = tile[nl * 81 + c];
  }
}

// Suffix-sum select over HISTB buckets: finds minimal suffix >= min(total, cap).
// Outputs (shared): bucket, selected count (suffix incl. bucket), count strictly above bucket.
__device__ __forceinline__ void suffix_select(unsigned* hist, unsigned* psum, int tid,
                                              unsigned cap, unsigned* s_bucket,
                                              unsigned* s_sel, unsigned* s_above,
                                              unsigned* out_total) {
  unsigned v = 0;
  const int hb = tid * (HISTB / 256);
#pragma unroll
  for (int t = 0; t < HISTB / 256; ++t) v += hist[hb + t];
  psum[tid] = v;
  __syncthreads();
  for (int off = 1; off < 256; off <<= 1) {
    unsigned o = (tid + off < 256) ? psum[tid + off] : 0u;
    __syncthreads();
    v += o;
    psum[tid] = v;
    __syncthreads();
  }
  const unsigned total = psum[0];
  *out_total = total;
  const unsigned target = total < cap ? total : cap;
  unsigned above = (tid < 255) ? psum[tid + 1] : 0u;
  if (total != 0u && v >= target && above < target) {  // exactly one thread qualifies
    unsigned acc = 0;
    for (int u = hb + HISTB / 256 - 1; u >= hb; --u) {
      acc += hist[u];
      if (above + acc >= target) {
        *s_bucket = (unsigned)u;
        *s_sel = above + acc;
        *s_above = above + acc - hist[u];
        break;
      }
    }
  }
  __syncthreads();
}

// Per-(b,c) NMS. STRIDE=1: coalesced transposed scores. STRIDE=NCLS: strided fallback.
template <int STRIDE>
__global__ __launch_bounds__(256) void k_nms(const float* __restrict__ boxes,
                                             const float* __restrict__ scores,
                                             float* __restrict__ keptScore,
                                             int* __restrict__ keptN,
                                             int* __restrict__ keptCount,
                                             int* __restrict__ flags) {
  // LDS layout (manual aliasing): hist[4096] u32 @0 aliased later by candbox[1024] f4;
  // keys u64[1024] @16384; keptbox f4[300] @24576; kn @29376; ksc @30576; psum @31776.
  __shared__ __align__(16) char smem[32800];
  unsigned* hist = (unsigned*)smem;
  float4* candbox = (float4*)smem;
  unsigned long long* keys = (unsigned long long*)(smem + 16384);
  float4* keptbox = (float4*)(smem + 24576);
  int* kn = (int*)(smem + 29376);
  float* ksc = (float*)(smem + 30576);
  unsigned* psum = (unsigned*)(smem + 31776);
  __shared__ unsigned s_bC, s_selC, s_aboveC, s_bF, s_selF, s_aboveF, s_cnt;

  const int tid = threadIdx.x;
  const int bc = blockIdx.x;
  const int b = bc / NCLS, c = bc % NCLS;
  const float* col = (STRIDE == 1) ? (scores + (size_t)bc * NBOX)
                                   : (scores + (size_t)b * NBOX * NCLS + c);

  for (int i = tid; i < HISTB; i += 256) hist[i] = 0u;
  if (tid == 0) s_cnt = 0u;
  __syncthreads();

  // Pass 1: coarse histogram (top 13 bits of score pattern).
  if (STRIDE == 1) {
    const float4* col4 = (const float4*)col;
    for (int q = tid; q < NBOX / 4; q += 256) {
      float4 v4 = col4[q];
      float vv[4] = {v4.x, v4.y, v4.z, v4.w};
#pragma unroll
      for (int e = 0; e < 4; ++e)
        if (vv[e] > SCORE_THR) atomicAdd(&hist[__float_as_uint(vv[e]) >> 19], 1u);
    }
  } else {
    for (int n = tid; n < NBOX; n += 256) {
      float s = col[(size_t)n * STRIDE];
      if (s > SCORE_THR) atomicAdd(&hist[__float_as_uint(s) >> 19], 1u);
    }
  }
  __syncthreads();

  unsigned totalC;
  suffix_select(hist, psum, tid, TARGETK, &s_bC, &s_selC, &s_aboveC, &totalC);

  if (totalC == 0u) {
    for (int r = tid; r < MAXDET; r += 256) {
      keptScore[bc * MAXDET + r] = -INFINITY;
      keptN[bc * MAXDET + r] = 0;
    }
    if (tid == 0) { keptCount[bc] = 0; flags[bc] = 0; }
    return;
  }

  const unsigned B0 = s_bC;
  const unsigned aboveC = s_aboveC;
  const unsigned target = totalC < TARGETK ? totalC : TARGETK;
  const unsigned need = target - aboveC;  // >= 1 by minimality of the coarse suffix

  // Pass 2: fine histogram (next 12 bits) over elements in coarse bucket B0.
  for (int i = tid; i < HISTB; i += 256) hist[i] = 0u;
  __syncthreads();
  if (STRIDE == 1) {
    const float4* col4 = (const float4*)col;
    for (int q = tid; q < NBOX / 4; q += 256) {
      float4 v4 = col4[q];
      float vv[4] = {v4.x, v4.y, v4.z, v4.w};
#pragma unroll
      for (int e = 0; e < 4; ++e) {
        if (vv[e] > SCORE_THR) {
          unsigned bits = __float_as_uint(vv[e]);
          if ((bits >> 19) == B0) atomicAdd(&hist[(bits >> 7) & 0xFFFu], 1u);
        }
      }
    }
  } else {
    for (int n = tid; n < NBOX; n += 256) {
      float s = col[(size_t)n * STRIDE];
      if (s > SCORE_THR) {
        unsigned bits = __float_as_uint(s);
        if ((bits >> 19) == B0) atomicAdd(&hist[(bits >> 7) & 0xFFFu], 1u);
      }
    }
  }
  __syncthreads();

  unsigned totalF;
  suffix_select(hist, psum, tid, need, &s_bF, &s_selF, &s_aboveF, &totalF);
  const unsigned F0 = s_bF;
  const unsigned selCount = aboveC + s_selF;

  if (selCount > CAP) {  // tie pile-up beyond capacity: exact slow path
    for (int r = tid; r < MAXDET; r += 256) {
      keptScore[bc * MAXDET + r] = -INFINITY;
      keptN[bc * MAXDET + r] = 0;
    }
    if (tid == 0) { keptCount[bc] = 0; flags[bc] = 1; }
    return;
  }

  // Pass 3: compact selected candidates into keys.
  if (STRIDE == 1) {
    const float4* col4 = (const float4*)col;
    for (int q = tid; q < NBOX / 4; q += 256) {
      float4 v4 = col4[q];
      float vv[4] = {v4.x, v4.y, v4.z, v4.w};
#pragma unroll
      for (int e = 0; e < 4; ++e) {
        if (vv[e] > SCORE_THR) {
          unsigned bits = __float_as_uint(vv[e]);
          unsigned cb = bits >> 19;
          if (cb > B0 || (cb == B0 && ((bits >> 7) & 0xFFFu) >= F0)) {
            unsigned pos = atomicAdd(&s_cnt, 1u);
            keys[pos] = ((unsigned long long)bits << 32) | (~(unsigned)(q * 4 + e));
          }
        }
      }
    }
  } else {
    for (int n = tid; n < NBOX; n += 256) {
      float s = col[(size_t)n * STRIDE];
      if (s > SCORE_THR) {
        unsigned bits = __float_as_uint(s);
        unsigned cb = bits >> 19;
        if (cb > B0 || (cb == B0 && ((bits >> 7) & 0xFFFu) >= F0)) {
          unsigned pos = atomicAdd(&s_cnt, 1u);
          keys[pos] = ((unsigned long long)bits << 32) | (~(unsigned)n);
        }
      }
    }
  }
  __syncthreads();
  for (int i = (int)selCount + tid; i < CAP; i += 256) keys[i] = 0ull;
  __syncthreads();

  // Bitonic sort ascending over CAP u64 keys (top candidates at the tail).
  for (int k = 2; k <= CAP; k <<= 1) {
    for (int j = k >> 1; j > 0; j >>= 1) {
      for (int i = tid; i < CAP; i += 256) {
        int ixj = i ^ j;
        if (ixj > i) {
          unsigned long long a = keys[i], bk = keys[ixj];
          bool asc = ((i & k) == 0);
          if (asc ? (a > bk) : (a < bk)) { keys[i] = bk; keys[ixj] = a; }
        }
      }
      __syncthreads();
    }
  }

  // Gather candidate boxes into LDS (position-aligned with keys). hist region is dead now.
  for (int i = tid; i < CAP; i += 256) {
    if (i >= (int)(CAP - selCount)) {
      unsigned n = ~((unsigned)keys[i]);
      candbox[i] = ((const float4*)boxes)[(size_t)b * NBOX + n];
    }
  }
  __syncthreads();

  // Tile-parallel greedy walk (wave 0): 64 sorted candidates per step.
  if (tid < 64) {
    const int lane = tid;
    int kept = 0;
    const unsigned ntile = (selCount + 63u) >> 6;
    for (unsigned t = 0; t < ntile && kept < MAXDET; ++t) {
      const unsigned r = t * 64u + (unsigned)lane;   // rank in descending order
      const bool valid = r < selCount;
      const int si = (CAP - 1) - (int)r;
      float4 mybox = candbox[si];
      unsigned long long mykey = keys[si];
      // suppression by previously-kept boxes (lanes parallel, broadcast LDS reads)
      bool prior = false;
      for (int k = 0; k < kept; ++k) {
        float4 kb = keptbox[k];
        if (iou_gt_half(kb.x, kb.y, kb.z, kb.w, mybox.x, mybox.y, mybox.z, mybox.w))
          prior = true;
      }
      // in-tile pairwise: bit e set iff earlier candidate e would suppress me
      unsigned long long m = 0ull;
      for (int e = 0; e < 64; ++e) {
        float4 eb = candbox[(CAP - 1) - (int)(t * 64u + (unsigned)e)];
        if (e < lane && iou_gt_half(eb.x, eb.y, eb.z, eb.w, mybox.x, mybox.y, mybox.z, mybox.w))
          m |= 1ull << e;
      }
      // uniform greedy resolution over the tile
      unsigned long long remaining = __ballot(valid && !prior);
      unsigned long long keptmask = 0ull;
      while (remaining != 0ull && kept + (int)__popcll(keptmask) < MAXDET) {
        int j = __ffsll((long long)remaining) - 1;
        keptmask |= 1ull << j;
        remaining &= ~(1ull << j);
        unsigned long long supj = __ballot((m >> j) & 1ull);
        remaining &= ~supj;
      }
      if ((keptmask >> lane) & 1ull) {
        int pos = kept + (int)__popcll(keptmask & ((1ull << lane) - 1ull));
        keptbox[pos] = mybox;
        kn[pos] = (int)(~((unsigned)mykey));
        ksc[pos] = __uint_as_float((unsigned)(mykey >> 32));
      }
      kept += (int)__popcll(keptmask);
      __asm__ volatile("s_waitcnt lgkmcnt(0)" ::: "memory");
      __builtin_amdgcn_sched_barrier(0);
    }
    for (int rr = lane; rr < MAXDET; rr += 64) {
      keptScore[bc * MAXDET + rr] = (rr < kept) ? ksc[rr] : -INFINITY;
      keptN[bc * MAXDET + rr] = (rr < kept) ? kn[rr] : 0;
    }
    if (lane == 0) {
      keptCount[bc] = kept;
      flags[bc] = (kept < MAXDET && selCount < totalC) ? 1 : 0;  // prefix exhausted
    }
  }
}

// Exact reference-style greedy NMS for flagged problems (expected: none fire).
__global__ __launch_bounds__(256) void k_slow(const float* __restrict__ boxes,
                                              const float* __restrict__ cls,
                                              float* __restrict__ keptScore,
                                              int* __restrict__ keptN,
                                              int* __restrict__ keptCount,
                                              const int* __restrict__ flags) {
  const int bc = blockIdx.x;
  if (flags[bc] == 0) return;
  const int tid = threadIdx.x;
  const int b = bc / NCLS, c = bc % NCLS;
  const float* col = cls + (size_t)b * NBOX * NCLS + c;
  __shared__ unsigned int sup[(NBOX + 31) / 32];
  __shared__ unsigned long long red[256];
  __shared__ float4 sbx;
  __shared__ int s_kept;
  for (int i = tid; i < (NBOX + 31) / 32; i += 256) sup[i] = 0u;
  if (tid == 0) s_kept = 0;
  __syncthreads();
  for (int it = 0; it < MAXDET; ++it) {
    unsigned long long best = 0ull;
    for (int n = tid; n < NBOX; n += 256) {
      if ((sup[n >> 5] >> (n & 31)) & 1u) continue;
      float s = col[(size_t)n * NCLS];
      if (s > SCORE_THR) {
        unsigned long long key = ((unsigned long long)__float_as_uint(s) << 32) | (~(unsigned)n);
        if (key > best) best = key;
      }
    }
    red[tid] = best;
    __syncthreads();
    for (int off = 128; off > 0; off >>= 1) {
      if (tid < off) { unsigned long long o = red[tid + off]; if (o > red[tid]) red[tid] = o; }
      __syncthreads();
    }
    unsigned long long win = red[0];
    if (win == 0ull) break;
    unsigned int nw = ~((unsigned int)win);
    if (tid == 0) {
      int k = s_kept;
      keptScore[bc * MAXDET + k] = __uint_as_float((unsigned)(win >> 32));
      keptN[bc * MAXDET + k] = (int)nw;
      s_kept = k + 1;
      sbx = ((const float4*)boxes)[(size_t)b * NBOX + nw];
    }
    __syncthreads();
    float4 bx = sbx;
    for (int n = tid; n < NBOX; n += 256) {
      float4 cb = ((const float4*)boxes)[(size_t)b * NBOX + n];
      if (iou_gt_half(bx.x, bx.y, bx.z, bx.w, cb.x, cb.y, cb.z, cb.w))
        atomicOr(&sup[n >> 5], 1u << (n & 31));
    }
    if (tid == 0) atomicOr(&sup[nw >> 5], 1u << (nw & 31));
    __syncthreads();
  }
  __syncthreads();
  const int kept = s_kept;
  for (int r = kept + tid; r < MAXDET; r += 256) {
    keptScore[bc * MAXDET + r] = -INFINITY;
    keptN[bc * MAXDET + r] = 0;
  }
  if (tid == 0) keptCount[bc] = kept;
}

// Per-batch 80-way sorted-list merge (= lax.top_k with flat-index tie-break) + outputs.
__global__ __launch_bounds__(256) void k_out(const float* __restrict__ boxes,
                                             const float* __restrict__ rel,
                                             const float* __restrict__ keptScore,
                                             const int* __restrict__ keptN,
                                             float* __restrict__ out) {
  __shared__ float sel_s[MAXDET];
  __shared__ int sel_c[MAXDET];
  __shared__ int sel_slot[MAXDET];
  const int tid = threadIdx.x;
  const int b = blockIdx.x;

  if (tid < 64) {
    const int lane = tid;
    const int c0 = lane;
    const int c1 = 64 + lane;
    const bool has1 = (c1 < NCLS);
    const float* ls0 = keptScore + ((size_t)b * NCLS + c0) * MAXDET;
    const float* ls1 = keptScore + ((size_t)b * NCLS + (has1 ? c1 : c0)) * MAXDET;
    int h0 = 0, h1 = 0;
    float v0 = ls0[0], w0 = ls0[1];
    float v1 = has1 ? ls1[0] : -INFINITY;
    float w1 = has1 ? ls1[1] : -INFINITY;
    for (int r = 0; r < MAXDET; ++r) {
      float bs; int bcl;
      if (has1 && v1 > v0) { bs = v1; bcl = c1; } else { bs = v0; bcl = c0; }
#pragma unroll
      for (int off = 32; off > 0; off >>= 1) {
        float os = __shfl_xor(bs, off);
        int oc = __shfl_xor(bcl, off);
        if (os > bs || (os == bs && oc < bcl)) { bs = os; bcl = oc; }
      }
      if (bcl == c0) {
        sel_s[r] = bs; sel_c[r] = bcl; sel_slot[r] = h0;
        ++h0; v0 = w0; w0 = (h0 + 1 < MAXDET) ? ls0[h0 + 1] : -INFINITY;
      } else if (has1 && bcl == c1) {
        sel_s[r] = bs; sel_c[r] = bcl; sel_slot[r] = h1;
        ++h1; v1 = w1; w1 = (h1 + 1 < MAXDET) ? ls1[h1 + 1] : -INFINITY;
      }
    }
  }
  __syncthreads();

  for (int r = tid; r < MAXDET; r += 256) {
    float s = sel_s[r];
    int c = sel_c[r];
    int slot = sel_slot[r];
    bool valid = (s != -INFINITY);
    int n = valid ? keptN[((size_t)b * NCLS + c) * MAXDET + slot] : 0;
    size_t nb = (size_t)b * NBOX + (unsigned)n;
    float4 ob;
    if (valid) ob = ((const float4*)boxes)[nb];
    else { ob.x = ob.y = ob.z = ob.w = -1.0f; }
    ((float4*)out)[(size_t)b * MAXDET + r] = ob;
    const int sbase = NBATCH * MAXDET * 4;
    out[sbase + b * MAXDET + r] = valid ? s : -1.0f;
    out[sbase + NBATCH * MAXDET + b * MAXDET + r] = valid ? (float)c : -1.0f;
    float pm = -1.0f, pl = -1.0f;
    if (valid) {
      const float* rp = rel + nb * NREL;
      float best = rp[0]; int bi = 0;
      for (int p = 1; p < NREL; ++p) { float vv = rp[p]; if (vv > best) { best = vv; bi = p; } }
      pm = best; pl = (float)bi;
    }
    out[sbase + 2 * NBATCH * MAXDET + b * MAXDET + r] = pm;
    out[sbase + 3 * NBATCH * MAXDET + b * MAXDET + r] = pl;
  }
}

extern "C" void kernel_launch(void* const* d_in, const int* in_sizes, int n_in,
                              void* d_out, int out_size, void* d_ws, size_t ws_size,
                              hipStream_t stream) {
  (void)in_sizes; (void)n_in; (void)out_size;
  const float* boxes = (const float*)d_in[0];
  const float* cls   = (const float*)d_in[1];
  const float* rel   = (const float*)d_in[2];
  float* out = (float*)d_out;
  char* ws = (char*)d_ws;

  const size_t trBytes = (size_t)NBATCH * NCLS * NBOX * 4;             // 51.2 MB
  const size_t keptBytes = (size_t)NBATCH * NCLS * MAXDET * 8 + NBATCH * NCLS * 8;
  const bool useTr = ws_size >= trBytes + keptBytes;

  float* colS = (float*)ws;
  char* kbase = useTr ? (ws + trBytes) : ws;
  float* keptScore = (float*)kbase;
  int* keptN = (int*)(kbase + (size_t)NBATCH * NCLS * MAXDET * 4);
  int* keptCount = (int*)(kbase + (size_t)NBATCH * NCLS * MAXDET * 8);
  int* flags = keptCount + NBATCH * NCLS;

  if (useTr) {
    k_tr<<<dim3((NBOX + 63) / 64, NBATCH), 256, 0, stream>>>(cls, colS);
    k_nms<1><<<NBATCH * NCLS, 256, 0, stream>>>(boxes, colS, keptScore, keptN, keptCount, flags);
  } else {
    k_nms<NCLS><<<NBATCH * NCLS, 256, 0, stream>>>(boxes, cls, keptScore, keptN, keptCount, flags);
  }
  k_slow<<<NBATCH * NCLS, 256, 0, stream>>>(boxes, cls, keptScore, keptN, keptCount, flags);
  k_out<<<NBATCH, 256, 0, stream>>>(boxes, rel, keptScore, keptN, out);
}

// Round 3
// 234.946 us; speedup vs baseline: 4.1187x; 1.9428x over previous
//
#include <hip/hip_runtime.h>
#include <hip/hip_bf16.h>
#include <math.h>

#define NBATCH 8
#define NBOX   20000
#define NCLS   80
#define NREL   51
#define MAXDET 300
#define CAP    1024
#define TARGETK 1000u
#define HISTB  4096
#define SCORE_THR 0.05f

// IoU > 0.5, bit-exact vs numpy (no FMA contraction, IEEE div).
// a = already-selected (earlier) box, b = candidate — matches reference operand roles.
__device__ __forceinline__ bool iou_gt_half(float ax1, float ay1, float ax2, float ay2,
                                            float bx1, float by1, float bx2, float by2) {
  float ix1 = fmaxf(ax1, bx1);
  float iy1 = fmaxf(ay1, by1);
  float ix2 = fminf(ax2, bx2);
  float iy2 = fminf(ay2, by2);
  float dw = fmaxf(__fsub_rn(ix2, ix1), 0.0f);
  float dh = fmaxf(__fsub_rn(iy2, iy1), 0.0f);
  float inter = __fmul_rn(dw, dh);
  float aa = __fmul_rn(__fsub_rn(ax2, ax1), __fsub_rn(ay2, ay1));
  float ab = __fmul_rn(__fsub_rn(bx2, bx1), __fsub_rn(by2, by1));
  float uni = __fsub_rn(__fadd_rn(aa, ab), inter);
  if (!(uni > 0.0f)) return false;
  return __fdiv_rn(inter, uni) > 0.5f;
}

// Transpose cls (B,N,C) -> colS (B,C,N). float4 both directions through padded LDS tile.
__global__ __launch_bounds__(256) void k_tr(const float* __restrict__ cls,
                                            float* __restrict__ colS) {
  __shared__ float tile[NCLS * 65];
  const int tid = threadIdx.x;
  const int b = blockIdx.y;
  const int n0 = blockIdx.x * 64;
  const int rows = (NBOX - n0) < 64 ? (NBOX - n0) : 64;   // 64 (or 32 for last block)
  const float4* src4 = (const float4*)(cls + ((size_t)b * NBOX + n0) * NCLS);
  const int nq = rows * (NCLS / 4);
  for (int i = tid; i < nq; i += 256) {
    int rr = i / (NCLS / 4);
    int c4 = i - rr * (NCLS / 4);
    float4 v = src4[i];
    tile[(c4 * 4 + 0) * 65 + rr] = v.x;
    tile[(c4 * 4 + 1) * 65 + rr] = v.y;
    tile[(c4 * 4 + 2) * 65 + rr] = v.z;
    tile[(c4 * 4 + 3) * 65 + rr] = v.w;
  }
  __syncthreads();
  float4* dst4 = (float4*)colS;
  for (int i = tid; i < NCLS * 16; i += 256) {
    int c = i >> 4, nl = i & 15;
    if (nl * 4 < rows) {
      float4 v;
      v.x = tile[c * 65 + nl * 4 + 0];
      v.y = tile[c * 65 + nl * 4 + 1];
      v.z = tile[c * 65 + nl * 4 + 2];
      v.w = tile[c * 65 + nl * 4 + 3];
      dst4[(((size_t)b * NCLS + c) * NBOX + n0) / 4 + nl] = v;
    }
  }
}

// Suffix-sum select over HISTB buckets: minimal suffix >= min(total, cap).
__device__ __forceinline__ void suffix_select(unsigned* hist, unsigned* psum, int tid,
                                              unsigned cap, unsigned* s_bucket,
                                              unsigned* s_sel, unsigned* s_above,
                                              unsigned* out_total) {
  unsigned v = 0;
  const int hb = tid * (HISTB / 256);
#pragma unroll
  for (int t = 0; t < HISTB / 256; ++t) v += hist[hb + t];
  psum[tid] = v;
  __syncthreads();
  for (int off = 1; off < 256; off <<= 1) {
    unsigned o = (tid + off < 256) ? psum[tid + off] : 0u;
    __syncthreads();
    v += o;
    psum[tid] = v;
    __syncthreads();
  }
  const unsigned total = psum[0];
  *out_total = total;
  const unsigned target = total < cap ? total : cap;
  unsigned above = (tid < 255) ? psum[tid + 1] : 0u;
  if (total != 0u && v >= target && above < target) {  // exactly one thread qualifies
    unsigned acc = 0;
    for (int u = hb + HISTB / 256 - 1; u >= hb; --u) {
      acc += hist[u];
      if (above + acc >= target) {
        *s_bucket = (unsigned)u;
        *s_sel = above + acc;
        *s_above = above + acc - hist[u];
        break;
      }
    }
  }
  __syncthreads();
}

// Per-(b,c) NMS. STRIDE=1: coalesced transposed scores. STRIDE=NCLS: strided fallback.
template <int STRIDE>
__global__ __launch_bounds__(256) void k_nms(const float* __restrict__ boxes,
                                             const float* __restrict__ scores,
                                             float* __restrict__ keptScore,
                                             int* __restrict__ keptN,
                                             int* __restrict__ keptCount,
                                             int* __restrict__ flags) {
  // hist[4096] u32 @0 aliased later by candbox[1024] f4; keys u64[1024] @16384;
  // keptbox f4[300] @24576; kn @29376; ksc @30576; psum @31776.
  __shared__ __align__(16) char smem[32800];
  unsigned* hist = (unsigned*)smem;
  float4* candbox = (float4*)smem;
  unsigned long long* keys = (unsigned long long*)(smem + 16384);
  float4* keptbox = (float4*)(smem + 24576);
  int* kn = (int*)(smem + 29376);
  float* ksc = (float*)(smem + 30576);
  unsigned* psum = (unsigned*)(smem + 31776);
  __shared__ unsigned long long supW[4];
  __shared__ unsigned long long mpart[4][64];
  __shared__ unsigned s_bC, s_selC, s_aboveC, s_bF, s_selF, s_aboveF, s_cnt;
  __shared__ int s_kept;

  const int tid = threadIdx.x;
  const int bc = blockIdx.x;
  const int b = bc / NCLS, c = bc % NCLS;
  const float* col = (STRIDE == 1) ? (scores + (size_t)bc * NBOX)
                                   : (scores + (size_t)b * NBOX * NCLS + c);

  for (int i = tid; i < HISTB; i += 256) hist[i] = 0u;
  if (tid == 0) s_cnt = 0u;
  __syncthreads();

  // Pass 1: coarse histogram (top 13 bits).
  if (STRIDE == 1) {
    const float4* col4 = (const float4*)col;
#pragma unroll 4
    for (int q = tid; q < NBOX / 4; q += 256) {
      float4 v4 = col4[q];
      float vv[4] = {v4.x, v4.y, v4.z, v4.w};
#pragma unroll
      for (int e = 0; e < 4; ++e)
        if (vv[e] > SCORE_THR) atomicAdd(&hist[__float_as_uint(vv[e]) >> 19], 1u);
    }
  } else {
    for (int n = tid; n < NBOX; n += 256) {
      float s = col[(size_t)n * STRIDE];
      if (s > SCORE_THR) atomicAdd(&hist[__float_as_uint(s) >> 19], 1u);
    }
  }
  __syncthreads();

  unsigned totalC;
  suffix_select(hist, psum, tid, TARGETK, &s_bC, &s_selC, &s_aboveC, &totalC);

  if (totalC == 0u) {
    for (int r = tid; r < MAXDET; r += 256) {
      keptScore[bc * MAXDET + r] = -INFINITY;
      keptN[bc * MAXDET + r] = 0;
    }
    if (tid == 0) { keptCount[bc] = 0; flags[bc] = 0; }
    return;
  }

  const unsigned B0 = s_bC;
  const unsigned aboveC = s_aboveC;
  const unsigned target = totalC < TARGETK ? totalC : TARGETK;
  const unsigned need = target - aboveC;  // >= 1 by minimality

  // Pass 2: fine histogram (next 12 bits) within coarse bucket B0.
  for (int i = tid; i < HISTB; i += 256) hist[i] = 0u;
  __syncthreads();
  if (STRIDE == 1) {
    const float4* col4 = (const float4*)col;
#pragma unroll 4
    for (int q = tid; q < NBOX / 4; q += 256) {
      float4 v4 = col4[q];
      float vv[4] = {v4.x, v4.y, v4.z, v4.w};
#pragma unroll
      for (int e = 0; e < 4; ++e) {
        if (vv[e] > SCORE_THR) {
          unsigned bits = __float_as_uint(vv[e]);
          if ((bits >> 19) == B0) atomicAdd(&hist[(bits >> 7) & 0xFFFu], 1u);
        }
      }
    }
  } else {
    for (int n = tid; n < NBOX; n += 256) {
      float s = col[(size_t)n * STRIDE];
      if (s > SCORE_THR) {
        unsigned bits = __float_as_uint(s);
        if ((bits >> 19) == B0) atomicAdd(&hist[(bits >> 7) & 0xFFFu], 1u);
      }
    }
  }
  __syncthreads();

  unsigned totalF;
  suffix_select(hist, psum, tid, need, &s_bF, &s_selF, &s_aboveF, &totalF);
  const unsigned F0 = s_bF;
  const unsigned selCount = aboveC + s_selF;

  if (selCount > CAP) {  // tie pile-up beyond capacity: exact slow path
    for (int r = tid; r < MAXDET; r += 256) {
      keptScore[bc * MAXDET + r] = -INFINITY;
      keptN[bc * MAXDET + r] = 0;
    }
    if (tid == 0) { keptCount[bc] = 0; flags[bc] = 1; }
    return;
  }

  // Pass 3: compact selected candidates into keys.
  if (STRIDE == 1) {
    const float4* col4 = (const float4*)col;
#pragma unroll 4
    for (int q = tid; q < NBOX / 4; q += 256) {
      float4 v4 = col4[q];
      float vv[4] = {v4.x, v4.y, v4.z, v4.w};
#pragma unroll
      for (int e = 0; e < 4; ++e) {
        if (vv[e] > SCORE_THR) {
          unsigned bits = __float_as_uint(vv[e]);
          unsigned cb = bits >> 19;
          if (cb > B0 || (cb == B0 && ((bits >> 7) & 0xFFFu) >= F0)) {
            unsigned pos = atomicAdd(&s_cnt, 1u);
            keys[pos] = ((unsigned long long)bits << 32) | (~(unsigned)(q * 4 + e));
          }
        }
      }
    }
  } else {
    for (int n = tid; n < NBOX; n += 256) {
      float s = col[(size_t)n * STRIDE];
      if (s > SCORE_THR) {
        unsigned bits = __float_as_uint(s);
        unsigned cb = bits >> 19;
        if (cb > B0 || (cb == B0 && ((bits >> 7) & 0xFFFu) >= F0)) {
          unsigned pos = atomicAdd(&s_cnt, 1u);
          keys[pos] = ((unsigned long long)bits << 32) | (~(unsigned)n);
        }
      }
    }
  }
  __syncthreads();
  for (int i = (int)selCount + tid; i < CAP; i += 256) keys[i] = 0ull;
  __syncthreads();

  // Bitonic sort ascending over CAP u64 keys (top candidates at the tail).
  for (int k = 2; k <= CAP; k <<= 1) {
    for (int j = k >> 1; j > 0; j >>= 1) {
      for (int i = tid; i < CAP; i += 256) {
        int ixj = i ^ j;
        if (ixj > i) {
          unsigned long long a = keys[i], bk = keys[ixj];
          bool asc = ((i & k) == 0);
          if (asc ? (a > bk) : (a < bk)) { keys[i] = bk; keys[ixj] = a; }
        }
      }
      __syncthreads();
    }
  }

  // Gather candidate boxes (position-aligned with sorted keys). hist region dead.
  for (int i = tid; i < (int)selCount; i += 256) {
    unsigned n = ~((unsigned)keys[CAP - 1 - i]);
    candbox[CAP - 1 - i] = ((const float4*)boxes)[(size_t)b * NBOX + n];
  }
  if (tid == 0) s_kept = 0;
  __syncthreads();

  // Tile-parallel greedy walk — 4 waves cooperate per 64-candidate tile.
  const int lane = tid & 63;
  const int w = tid >> 6;
  const unsigned ntile = (selCount + 63u) >> 6;
  for (unsigned t = 0; t < ntile; ++t) {
    const int kept0 = s_kept;              // uniform (post-barrier)
    if (kept0 >= MAXDET) break;
    const unsigned r = t * 64u + (unsigned)lane;
    const bool valid = r < selCount;
    float4 mybox = candbox[valid ? (CAP - 1 - (int)r) : (CAP - 1)];
    // phase 1: prior-kept suppression, wave w handles kept indices w::4
    bool sup = false;
#pragma unroll 4
    for (int k = w; k < kept0; k += 4) {
      float4 kb = keptbox[k];
      if (iou_gt_half(kb.x, kb.y, kb.z, kb.w, mybox.x, mybox.y, mybox.z, mybox.w)) sup = true;
    }
    unsigned long long bal = __ballot(sup);
    if (lane == 0) supW[w] = bal;
    // phase 2: in-tile pairwise mask, wave w covers e in [16w, 16w+16)
    unsigned long long mw = 0ull;
    const int ebase = w * 16;
#pragma unroll
    for (int ee = 0; ee < 16; ++ee) {
      const int e = ebase + ee;
      float4 eb = candbox[CAP - 1 - (int)(t * 64u) - e];
      if (e < lane && iou_gt_half(eb.x, eb.y, eb.z, eb.w, mybox.x, mybox.y, mybox.z, mybox.w))
        mw |= 1ull << e;
    }
    mpart[w][lane] = mw;
    __syncthreads();
    if (w == 0) {
      unsigned long long prior = supW[0] | supW[1] | supW[2] | supW[3];
      unsigned long long m = mpart[0][lane] | mpart[1][lane] | mpart[2][lane] | mpart[3][lane];
      unsigned long long remaining = __ballot(valid) & ~prior;
      unsigned long long keptmask = 0ull;
      const int room = MAXDET - kept0;
      while (remaining != 0ull && (int)__popcll(keptmask) < room) {
        int j = __ffsll((long long)remaining) - 1;
        keptmask |= 1ull << j;
        remaining &= ~(1ull << j);
        unsigned long long supj = __ballot(((m >> j) & 1ull) != 0ull);
        remaining &= ~supj;
      }
      if ((keptmask >> lane) & 1ull) {
        int pos = kept0 + (int)__popcll(keptmask & ((1ull << lane) - 1ull));
        unsigned long long mykey = keys[CAP - 1 - (int)r];
        keptbox[pos] = mybox;
        kn[pos] = (int)(~((unsigned)mykey));
        ksc[pos] = __uint_as_float((unsigned)(mykey >> 32));
      }
      if (lane == 0) s_kept = kept0 + (int)__popcll(keptmask);
    }
    __syncthreads();
  }

  const int kept = s_kept;
  for (int rr = tid; rr < MAXDET; rr += 256) {
    keptScore[bc * MAXDET + rr] = (rr < kept) ? ksc[rr] : -INFINITY;
    keptN[bc * MAXDET + rr] = (rr < kept) ? kn[rr] : 0;
  }
  if (tid == 0) {
    keptCount[bc] = kept;
    flags[bc] = (kept < MAXDET && selCount < totalC) ? 1 : 0;  // prefix exhausted
  }
}

// Exact reference-style greedy NMS for flagged problems (expected: none fire).
__global__ __launch_bounds__(256) void k_slow(const float* __restrict__ boxes,
                                              const float* __restrict__ cls,
                                              float* __restrict__ keptScore,
                                              int* __restrict__ keptN,
                                              int* __restrict__ keptCount,
                                              const int* __restrict__ flags) {
  const int bc = blockIdx.x;
  if (flags[bc] == 0) return;
  const int tid = threadIdx.x;
  const int b = bc / NCLS, c = bc % NCLS;
  const float* col = cls + (size_t)b * NBOX * NCLS + c;
  __shared__ unsigned int sup[(NBOX + 31) / 32];
  __shared__ unsigned long long red[256];
  __shared__ float4 sbx;
  __shared__ int s_kept;
  for (int i = tid; i < (NBOX + 31) / 32; i += 256) sup[i] = 0u;
  if (tid == 0) s_kept = 0;
  __syncthreads();
  for (int it = 0; it < MAXDET; ++it) {
    unsigned long long best = 0ull;
    for (int n = tid; n < NBOX; n += 256) {
      if ((sup[n >> 5] >> (n & 31)) & 1u) continue;
      float s = col[(size_t)n * NCLS];
      if (s > SCORE_THR) {
        unsigned long long key = ((unsigned long long)__float_as_uint(s) << 32) | (~(unsigned)n);
        if (key > best) best = key;
      }
    }
    red[tid] = best;
    __syncthreads();
    for (int off = 128; off > 0; off >>= 1) {
      if (tid < off) { unsigned long long o = red[tid + off]; if (o > red[tid]) red[tid] = o; }
      __syncthreads();
    }
    unsigned long long win = red[0];
    if (win == 0ull) break;
    unsigned int nw = ~((unsigned int)win);
    if (tid == 0) {
      int k = s_kept;
      keptScore[bc * MAXDET + k] = __uint_as_float((unsigned)(win >> 32));
      keptN[bc * MAXDET + k] = (int)nw;
      s_kept = k + 1;
      sbx = ((const float4*)boxes)[(size_t)b * NBOX + nw];
    }
    __syncthreads();
    float4 bx = sbx;
    for (int n = tid; n < NBOX; n += 256) {
      float4 cb = ((const float4*)boxes)[(size_t)b * NBOX + n];
      if (iou_gt_half(bx.x, bx.y, bx.z, bx.w, cb.x, cb.y, cb.z, cb.w))
        atomicOr(&sup[n >> 5], 1u << (n & 31));
    }
    if (tid == 0) atomicOr(&sup[nw >> 5], 1u << (nw & 31));
    __syncthreads();
  }
  __syncthreads();
  const int kept = s_kept;
  for (int r = kept + tid; r < MAXDET; r += 256) {
    keptScore[bc * MAXDET + r] = -INFINITY;
    keptN[bc * MAXDET + r] = 0;
  }
  if (tid == 0) keptCount[bc] = kept;
}

// Per-batch global top-300 via 2-level histogram select + bitonic sort over <=1024 keys
// (key = score_bits<<32 | ~flat_idx -> exact lax.top_k order with lower-flat-index ties).
__global__ __launch_bounds__(256) void k_out(const float* __restrict__ boxes,
                                             const float* __restrict__ rel,
                                             const float* __restrict__ keptScore,
                                             const int* __restrict__ keptN,
                                             float* __restrict__ out) {
  __shared__ __align__(16) char smem[16384 + 8192 + 1024];
  unsigned* hist = (unsigned*)smem;
  unsigned long long* keys = (unsigned long long*)(smem + 16384);  // [1024]
  unsigned* psum = (unsigned*)(smem + 24576);
  __shared__ unsigned s_bC, s_selC, s_aboveC, s_bF, s_selF, s_aboveF, s_cnt, s_sz;
  const int tid = threadIdx.x;
  const int b = blockIdx.x;
  const int NTOT = NCLS * MAXDET;  // 24000
  const float* ks = keptScore + (size_t)b * NTOT;

  for (int i = tid; i < HISTB; i += 256) hist[i] = 0u;
  if (tid == 0) s_cnt = 0u;
  __syncthreads();
  const float4* ks4 = (const float4*)ks;
#pragma unroll 4
  for (int q = tid; q < NTOT / 4; q += 256) {
    float4 v4 = ks4[q];
    float vv[4] = {v4.x, v4.y, v4.z, v4.w};
#pragma unroll
    for (int e = 0; e < 4; ++e)
      if (vv[e] > 0.0f) atomicAdd(&hist[__float_as_uint(vv[e]) >> 19], 1u);  // kept scores > 0.05
  }
  __syncthreads();
  unsigned totalC;
  suffix_select(hist, psum, tid, (unsigned)MAXDET, &s_bC, &s_selC, &s_aboveC, &totalC);
  const unsigned target = totalC < (unsigned)MAXDET ? totalC : (unsigned)MAXDET;

  if (totalC != 0u) {
    const unsigned B0 = s_bC;
    const unsigned aboveC = s_aboveC;
    const unsigned need = target - aboveC;
    for (int i = tid; i < HISTB; i += 256) hist[i] = 0u;
    __syncthreads();
#pragma unroll 4
    for (int q = tid; q < NTOT / 4; q += 256) {
      float4 v4 = ks4[q];
      float vv[4] = {v4.x, v4.y, v4.z, v4.w};
#pragma unroll
      for (int e = 0; e < 4; ++e) {
        if (vv[e] > 0.0f) {
          unsigned bits = __float_as_uint(vv[e]);
          if ((bits >> 19) == B0) atomicAdd(&hist[(bits >> 7) & 0xFFFu], 1u);
        }
      }
    }
    __syncthreads();
    unsigned totalF;
    suffix_select(hist, psum, tid, need, &s_bF, &s_selF, &s_aboveF, &totalF);
    const unsigned F0 = s_bF;
    const unsigned selCount = aboveC + s_selF;

    if (selCount <= 1024u) {
#pragma unroll 4
      for (int q = tid; q < NTOT / 4; q += 256) {
        float4 v4 = ks4[q];
        float vv[4] = {v4.x, v4.y, v4.z, v4.w};
#pragma unroll
        for (int e = 0; e < 4; ++e) {
          if (vv[e] > 0.0f) {
            unsigned bits = __float_as_uint(vv[e]);
            unsigned cb = bits >> 19;
            if (cb > B0 || (cb == B0 && ((bits >> 7) & 0xFFFu) >= F0)) {
              unsigned pos = atomicAdd(&s_cnt, 1u);
              keys[pos] = ((unsigned long long)bits << 32) | (~(unsigned)(q * 4 + e));
            }
          }
        }
      }
      const int SZ = (selCount <= 512u) ? 512 : 1024;
      if (tid == 0) s_sz = (unsigned)SZ;
      __syncthreads();
      for (int i = (int)selCount + tid; i < SZ; i += 256) keys[i] = 0ull;
      __syncthreads();
      for (int k = 2; k <= SZ; k <<= 1) {
        for (int j = k >> 1; j > 0; j >>= 1) {
          for (int i = tid; i < SZ; i += 256) {
            int ixj = i ^ j;
            if (ixj > i) {
              unsigned long long a = keys[i], bk = keys[ixj];
              bool asc = ((i & k) == 0);
              if (asc ? (a > bk) : (a < bk)) { keys[i] = bk; keys[ixj] = a; }
            }
          }
          __syncthreads();
        }
      }
    } else {
      // fallback: serial 80-way merge (only fires on >1024-way score ties)
      if (tid == 0) s_sz = 1024u;
      __syncthreads();
      if (tid < 64) {
        const int lane = tid;
        const int c0 = lane, c1 = 64 + lane;
        const bool has1 = (c1 < NCLS);
        const float* ls0 = keptScore + ((size_t)b * NCLS + c0) * MAXDET;
        const float* ls1 = keptScore + ((size_t)b * NCLS + (has1 ? c1 : c0)) * MAXDET;
        int h0 = 0, h1 = 0;
        float v0 = ls0[0], w0v = ls0[1];
        float v1 = has1 ? ls1[0] : -INFINITY;
        float w1v = has1 ? ls1[1] : -INFINITY;
        for (int r = 0; r < (int)target; ++r) {
          float bs; int bcl;
          if (has1 && v1 > v0) { bs = v1; bcl = c1; } else { bs = v0; bcl = c0; }
#pragma unroll
          for (int off = 32; off > 0; off >>= 1) {
            float os = __shfl_xor(bs, off);
            int oc = __shfl_xor(bcl, off);
            if (os > bs || (os == bs && oc < bcl)) { bs = os; bcl = oc; }
          }
          if (bcl == c0) {
            keys[1023 - r] = ((unsigned long long)__float_as_uint(bs) << 32) |
                             (~(unsigned)(c0 * MAXDET + h0));
            ++h0; v0 = w0v; w0v = (h0 + 1 < MAXDET) ? ls0[h0 + 1] : -INFINITY;
          } else if (has1 && bcl == c1) {
            keys[1023 - r] = ((unsigned long long)__float_as_uint(bs) << 32) |
                             (~(unsigned)(c1 * MAXDET + h1));
            ++h1; v1 = w1v; w1v = (h1 + 1 < MAXDET) ? ls1[h1 + 1] : -INFINITY;
          }
        }
      }
      __syncthreads();
    }
  }

  const int SZr = (totalC != 0u) ? (int)s_sz : 0;
  for (int r = tid; r < MAXDET; r += 256) {
    const bool valid = (unsigned)r < target;
    float s = -1.0f, pm = -1.0f, pl = -1.0f, cl = -1.0f;
    float4 ob; ob.x = ob.y = ob.z = ob.w = -1.0f;
    if (valid) {
      unsigned long long key = keys[SZr - 1 - r];
      unsigned fp = ~((unsigned)key);
      int c = (int)(fp / MAXDET);
      int slot = (int)(fp - (unsigned)c * MAXDET);
      int n = keptN[((size_t)b * NCLS + c) * MAXDET + slot];
      s = __uint_as_float((unsigned)(key >> 32));
      cl = (float)c;
      size_t nb = (size_t)b * NBOX + (unsigned)n;
      ob = ((const float4*)boxes)[nb];
      const float* rp = rel + nb * NREL;
      float best = rp[0]; int bi = 0;
      for (int p = 1; p < NREL; ++p) { float vv = rp[p]; if (vv > best) { best = vv; bi = p; } }
      pm = best; pl = (float)bi;
    }
    ((float4*)out)[(size_t)b * MAXDET + r] = ob;
    const int sbase = NBATCH * MAXDET * 4;
    out[sbase + b * MAXDET + r] = s;
    out[sbase + NBATCH * MAXDET + b * MAXDET + r] = cl;
    out[sbase + 2 * NBATCH * MAXDET + b * MAXDET + r] = pm;
    out[sbase + 3 * NBATCH * MAXDET + b * MAXDET + r] = pl;
  }
}

extern "C" void kernel_launch(void* const* d_in, const int* in_sizes, int n_in,
                              void* d_out, int out_size, void* d_ws, size_t ws_size,
                              hipStream_t stream) {
  (void)in_sizes; (void)n_in; (void)out_size;
  const float* boxes = (const float*)d_in[0];
  const float* cls   = (const float*)d_in[1];
  const float* rel   = (const float*)d_in[2];
  float* out = (float*)d_out;
  char* ws = (char*)d_ws;

  const size_t trBytes = (size_t)NBATCH * NCLS * NBOX * 4;             // 51.2 MB
  const size_t keptBytes = (size_t)NBATCH * NCLS * MAXDET * 8 + NBATCH * NCLS * 8;
  const bool useTr = ws_size >= trBytes + keptBytes;

  float* colS = (float*)ws;
  char* kbase = useTr ? (ws + trBytes) : ws;
  float* keptScore = (float*)kbase;
  int* keptN = (int*)(kbase + (size_t)NBATCH * NCLS * MAXDET * 4);
  int* keptCount = (int*)(kbase + (size_t)NBATCH * NCLS * MAXDET * 8);
  int* flags = keptCount + NBATCH * NCLS;

  if (useTr) {
    k_tr<<<dim3((NBOX + 63) / 64, NBATCH), 256, 0, stream>>>(cls, colS);
    k_nms<1><<<NBATCH * NCLS, 256, 0, stream>>>(boxes, colS, keptScore, keptN, keptCount, flags);
  } else {
    k_nms<NCLS><<<NBATCH * NCLS, 256, 0, stream>>>(boxes, cls, keptScore, keptN, keptCount, flags);
  }
  k_slow<<<NBATCH * NCLS, 256, 0, stream>>>(boxes, cls, keptScore, keptN, keptCount, flags);
  k_out<<<NBATCH, 256, 0, stream>>>(boxes, rel, keptScore, keptN, out);
}

// Round 4
// 202.216 us; speedup vs baseline: 4.7853x; 1.1619x over previous
//
#include <hip/hip_runtime.h>
#include <hip/hip_bf16.h>
#include <math.h>

#define NBATCH 8
#define NBOX   20000
#define NCLS   80
#define NREL   51
#define MAXDET 300
#define CAP    1024
#define SIDECAP 2048
#define TARGETK 1000u
#define SCORE_THR 0.05f

typedef unsigned long long u64;
typedef unsigned int u32;

// IoU > 0.5, bit-exact vs numpy. a = already-selected box (+ its area), b = candidate.
__device__ __forceinline__ bool iou_sup(float ax1, float ay1, float ax2, float ay2, float aarea,
                                        float bx1, float by1, float bx2, float by2, float barea) {
  float ix1 = fmaxf(ax1, bx1);
  float iy1 = fmaxf(ay1, by1);
  float ix2 = fminf(ax2, bx2);
  float iy2 = fminf(ay2, by2);
  float dw = fmaxf(__fsub_rn(ix2, ix1), 0.0f);
  float dh = fmaxf(__fsub_rn(iy2, iy1), 0.0f);
  float inter = __fmul_rn(dw, dh);
  float uni = __fsub_rn(__fadd_rn(aarea, barea), inter);
  if (!(uni > 0.0f)) return false;
  return __fdiv_rn(inter, uni) > 0.5f;
}

__device__ __forceinline__ bool iou_gt_half(float ax1, float ay1, float ax2, float ay2,
                                            float bx1, float by1, float bx2, float by2) {
  float aa = __fmul_rn(__fsub_rn(ax2, ax1), __fsub_rn(ay2, ay1));
  float ab = __fmul_rn(__fsub_rn(bx2, bx1), __fsub_rn(by2, by1));
  return iou_sup(ax1, ay1, ax2, ay2, aa, bx1, by1, bx2, by2, ab);
}

#define CEXR(x, y, asc) { bool sw_ = (asc) ? ((x) > (y)) : ((x) < (y)); \
                          if (sw_) { u64 t_ = (x); (x) = (y); (y) = t_; } }

// Bitonic sort ascending over SZ u64 keys in LDS; 4 elems/thread; j<=2 passes in registers.
__device__ __forceinline__ void bitonic_sort(u64* keys, int SZ, int tid) {
  for (int k = 2; k <= SZ; k <<= 1) {
    for (int j = k >> 1; j >= 4; j >>= 1) {
      for (int v = tid; v < (SZ >> 1); v += 256) {
        int i = ((v & ~(j - 1)) << 1) | (v & (j - 1));
        int p = i | j;
        bool asc = ((i & k) == 0);
        u64 a = keys[i], b = keys[p];
        bool sw = asc ? (a > b) : (a < b);
        if (sw) { keys[i] = b; keys[p] = a; }
      }
      __syncthreads();
    }
    if (tid < (SZ >> 2)) {
      ulonglong2* k2 = (ulonglong2*)keys;
      ulonglong2 lo = k2[tid * 2], hi = k2[tid * 2 + 1];
      u64 a = lo.x, b = lo.y, c = hi.x, d = hi.y;
      int i0 = tid << 2;
      if (k == 2) {
        CEXR(a, b, true); CEXR(c, d, false);
      } else {
        bool asc = ((i0 & k) == 0);
        CEXR(a, c, asc); CEXR(b, d, asc);  // j = 2
        CEXR(a, b, asc); CEXR(c, d, asc);  // j = 1
      }
      lo.x = a; lo.y = b; hi.x = c; hi.y = d;
      k2[tid * 2] = lo; k2[tid * 2 + 1] = hi;
    }
    __syncthreads();
  }
}

// Barrier-light suffix select over NB buckets: minimal suffix >= min(total, cap).
// sout: [0]=bucket [1]=sel(count in suffix incl bucket) [2]=above(strictly above) [3]=total.
template <int NB>
__device__ __forceinline__ void suffix_fast(const u32* hist, u32 cap, u32* wsum4, u32* sout) {
  const int tid = threadIdx.x, lane = tid & 63, w = tid >> 6;
  const int G = NB / 256;
  u32 v = 0;
  const int hb = tid * G;
#pragma unroll
  for (int t = 0; t < G; ++t) v += hist[hb + t];
  u32 s = v;
#pragma unroll
  for (int off = 1; off < 64; off <<= 1) {
    u32 t2 = __shfl_down(s, off);
    if (lane + off < 64) s += t2;
  }
  if (lane == 0) wsum4[w] = s;
  __syncthreads();
  u32 total = wsum4[0] + wsum4[1] + wsum4[2] + wsum4[3];
  u32 after = 0;
#pragma unroll
  for (int ww = 1; ww < 4; ++ww) if (ww > w) after += wsum4[ww];
  u32 inc = s + after;
  u32 exc = inc - v;
  if (tid == 0) sout[3] = total;
  u32 target = total < cap ? total : cap;
  if (total != 0u && inc >= target && exc < target) {  // exactly one thread
    u32 acc = exc;
    for (int u = hb + G - 1; u >= hb; --u) {
      acc += hist[u];
      if (acc >= target) { sout[0] = (u32)u; sout[1] = acc; sout[2] = acc - hist[u]; break; }
    }
  }
  __syncthreads();
}

// Transpose cls (B,N,C) -> colS (B,C,N).
__global__ __launch_bounds__(256) void k_tr(const float* __restrict__ cls,
                                            float* __restrict__ colS) {
  __shared__ float tile[NCLS * 65];
  const int tid = threadIdx.x;
  const int b = blockIdx.y;
  const int n0 = blockIdx.x * 64;
  const int rows = (NBOX - n0) < 64 ? (NBOX - n0) : 64;
  const float4* src4 = (const float4*)(cls + ((size_t)b * NBOX + n0) * NCLS);
  const int nq = rows * (NCLS / 4);
  for (int i = tid; i < nq; i += 256) {
    int rr = i / (NCLS / 4);
    int c4 = i - rr * (NCLS / 4);
    float4 v = src4[i];
    tile[(c4 * 4 + 0) * 65 + rr] = v.x;
    tile[(c4 * 4 + 1) * 65 + rr] = v.y;
    tile[(c4 * 4 + 2) * 65 + rr] = v.z;
    tile[(c4 * 4 + 3) * 65 + rr] = v.w;
  }
  __syncthreads();
  float4* dst4 = (float4*)colS;
  for (int i = tid; i < NCLS * 16; i += 256) {
    int c = i >> 4, nl = i & 15;
    if (nl * 4 < rows) {
      float4 v;
      v.x = tile[c * 65 + nl * 4 + 0];
      v.y = tile[c * 65 + nl * 4 + 1];
      v.z = tile[c * 65 + nl * 4 + 2];
      v.w = tile[c * 65 + nl * 4 + 3];
      dst4[(((size_t)b * NCLS + c) * NBOX + n0) / 4 + nl] = v;
    }
  }
}

template <int STRIDE>
__device__ __forceinline__ float4 load4s(const float* col, int q) {
  if (STRIDE == 1) return ((const float4*)col)[q];
  float4 v;
  v.x = col[(size_t)(q * 4 + 0) * STRIDE];
  v.y = col[(size_t)(q * 4 + 1) * STRIDE];
  v.z = col[(size_t)(q * 4 + 2) * STRIDE];
  v.w = col[(size_t)(q * 4 + 3) * STRIDE];
  return v;
}

// Per-(b,c) NMS: 2 global scans + LDS side-buffer fine select + bitonic + 4-wave walk.
template <int STRIDE>
__global__ __launch_bounds__(256) void k_nms(const float* __restrict__ boxes,
                                             const float* __restrict__ scores,
                                             float* __restrict__ keptScore,
                                             int* __restrict__ keptN,
                                             int* __restrict__ keptCount,
                                             int* __restrict__ flags) {
  // 0..16384: hist[4096]u32 -> side[2048]u64 -> candbox[1024]f4
  // 16384..24576: keys u64[1024]
  // 24576..28672: fineh[1024]u32 -> carea[1024]f32
  // 28672..33472: keptbox f4[300]; 33472: karea[300]; 34672: kn[300]; 35872: ksc[300]
  __shared__ __align__(16) char smem[37088];
  u32* hist = (u32*)smem;
  u64* side = (u64*)smem;
  float4* candbox = (float4*)smem;
  u64* keys = (u64*)(smem + 16384);
  u32* fineh = (u32*)(smem + 24576);
  float* carea = (float*)(smem + 24576);
  float4* keptbox = (float4*)(smem + 28672);
  float* karea = (float*)(smem + 33472);
  int* kn = (int*)(smem + 34672);
  float* ksc = (float*)(smem + 35872);
  __shared__ u32 wsum[4], selA[4], selB[4];
  __shared__ u64 supW[4];
  __shared__ u64 mpart[4][64];
  __shared__ u32 s_cnt, s_scnt;
  __shared__ int s_kept;

  const int tid = threadIdx.x;
  const int lane = tid & 63;
  const int w = tid >> 6;
  const u64 lmask = (1ull << lane) - 1ull;
  const int bc = blockIdx.x;
  const int b = bc / NCLS, c = bc % NCLS;
  const float* col = (STRIDE == 1) ? (scores + (size_t)bc * NBOX)
                                   : (scores + (size_t)b * NBOX * NCLS + c);

  for (int i = tid; i < 4096; i += 256) hist[i] = 0u;
  for (int i = tid; i < 1024; i += 256) fineh[i] = 0u;
  if (tid == 0) { s_cnt = 0u; s_scnt = 0u; s_kept = 0; }
  __syncthreads();

  // Pass 1: coarse histogram (top 13 bits), software-pipelined loads.
  for (int base = 0; base < NBOX / 4; base += 2048) {
    float4 v[8];
#pragma unroll
    for (int p = 0; p < 8; ++p) {
      int q = base + tid + (p << 8);
      if (q < NBOX / 4) v[p] = load4s<STRIDE>(col, q);
    }
#pragma unroll
    for (int p = 0; p < 8; ++p) {
      int q = base + tid + (p << 8);
      if (q < NBOX / 4) {
        float vv[4] = {v[p].x, v[p].y, v[p].z, v[p].w};
#pragma unroll
        for (int e = 0; e < 4; ++e)
          if (vv[e] > SCORE_THR) atomicAdd(&hist[__float_as_uint(vv[e]) >> 19], 1u);
      }
    }
  }
  __syncthreads();

  suffix_fast<4096>(hist, TARGETK, wsum, selA);
  const u32 totalC = selA[3];

  if (totalC == 0u) {
    for (int r = tid; r < MAXDET; r += 256) {
      keptScore[bc * MAXDET + r] = -INFINITY;
      keptN[bc * MAXDET + r] = 0;
    }
    if (tid == 0) { keptCount[bc] = 0; flags[bc] = 0; }
    return;
  }
  const u32 B0 = selA[0];
  const u32 aboveC = selA[2];
  const u32 target = totalC < TARGETK ? totalC : TARGETK;
  const u32 need = target - aboveC;  // >= 1 by minimality

  // Pass 2 (classify): cb>B0 -> keys (wave-aggregated); cb==B0 -> side buffer + fine hist.
  for (int base = 0; base < NBOX / 4; base += 2048) {
    float4 v[8];
#pragma unroll
    for (int p = 0; p < 8; ++p) {
      int q = base + tid + (p << 8);
      if (q < NBOX / 4) v[p] = load4s<STRIDE>(col, q);
    }
#pragma unroll
    for (int p = 0; p < 8; ++p) {
      int q = base + tid + (p << 8);
      if (q < NBOX / 4) {
        float vv[4] = {v[p].x, v[p].y, v[p].z, v[p].w};
#pragma unroll
        for (int e = 0; e < 4; ++e) {
          u32 bits = __float_as_uint(vv[e]);
          bool any = vv[e] > SCORE_THR;
          u32 cb = bits >> 19;
          u64 key = ((u64)bits << 32) | (~(u32)(q * 4 + e));
          bool hi = any && (cb > B0);
          u64 mh = __ballot(hi);
          if (mh) {
            u32 bs;
            if (lane == 0) bs = atomicAdd(&s_cnt, (u32)__popcll(mh));
            bs = __shfl(bs, 0);
            if (hi) keys[bs + (u32)__popcll(mh & lmask)] = key;
          }
          bool b0 = any && (cb == B0);
          u64 mb = __ballot(b0);
          if (mb) {
            u32 bs;
            if (lane == 0) bs = atomicAdd(&s_scnt, (u32)__popcll(mb));
            bs = __shfl(bs, 0);
            if (b0) {
              u32 pos = bs + (u32)__popcll(mb & lmask);
              if (pos < SIDECAP) side[pos] = key;
              atomicAdd(&fineh[(bits >> 9) & 0x3FFu], 1u);
            }
          }
        }
      }
    }
  }
  __syncthreads();
  const u32 sideCount = s_scnt;

  if (sideCount > SIDECAP) {  // pathological ties: exact slow path
    for (int r = tid; r < MAXDET; r += 256) {
      keptScore[bc * MAXDET + r] = -INFINITY;
      keptN[bc * MAXDET + r] = 0;
    }
    if (tid == 0) { keptCount[bc] = 0; flags[bc] = 1; }
    return;
  }

  // Fine select (10 more prefix bits) over the side buffer.
  suffix_fast<1024>(fineh, need, wsum, selB);
  const u32 F0 = selB[0];

  // Compact side -> keys (continuing s_cnt).
  const int iters = (int)((sideCount + 255u) >> 8);
  for (int it = 0; it < iters; ++it) {
    u32 idx = (u32)it * 256u + (u32)tid;
    bool act = idx < sideCount;
    u64 key = act ? side[idx] : 0ull;
    bool sel = act && (((key >> 41) & 0x3FFull) >= (u64)F0);
    u64 ms = __ballot(sel);
    if (ms) {
      u32 bs;
      if (lane == 0) bs = atomicAdd(&s_cnt, (u32)__popcll(ms));
      bs = __shfl(bs, 0);
      if (sel) {
        u32 pos = bs + (u32)__popcll(ms & lmask);
        if (pos < CAP) keys[pos] = key;
      }
    }
  }
  __syncthreads();
  const u32 selCount = s_cnt;

  if (selCount > CAP) {
    for (int r = tid; r < MAXDET; r += 256) {
      keptScore[bc * MAXDET + r] = -INFINITY;
      keptN[bc * MAXDET + r] = 0;
    }
    if (tid == 0) { keptCount[bc] = 0; flags[bc] = 1; }
    return;
  }

  for (int i = (int)selCount + tid; i < CAP; i += 256) keys[i] = 0ull;
  __syncthreads();

  bitonic_sort(keys, CAP, tid);

  // Gather candidate boxes + areas (side region dead; candbox/carea alias it).
  for (int i = tid; i < (int)selCount; i += 256) {
    int pos = CAP - 1 - i;
    u32 n = ~((u32)keys[pos]);
    float4 bb = ((const float4*)boxes)[(size_t)b * NBOX + n];
    candbox[pos] = bb;
    carea[pos] = __fmul_rn(__fsub_rn(bb.z, bb.x), __fsub_rn(bb.w, bb.y));
  }
  __syncthreads();

  // Tile-parallel greedy walk — 4 waves cooperate per 64-candidate tile.
  const u32 ntile = (selCount + 63u) >> 6;
  for (u32 t = 0; t < ntile; ++t) {
    const int kept0 = s_kept;
    if (kept0 >= MAXDET) break;
    const u32 r = t * 64u + (u32)lane;
    const bool valid = r < selCount;
    const int si = valid ? (CAP - 1 - (int)r) : (CAP - 1);
    float4 mybox = candbox[si];
    float marea = carea[si];
    // phase 1: prior-kept suppression (wave w covers kept indices w::4)
    bool sup = false;
    for (int k = w; k < kept0; k += 4) {
      float4 kb = keptbox[k];
      if (iou_sup(kb.x, kb.y, kb.z, kb.w, karea[k], mybox.x, mybox.y, mybox.z, mybox.w, marea))
        sup = true;
    }
    u64 bal = __ballot(sup);
    if (lane == 0) supW[w] = bal;
    // phase 2: in-tile pairwise mask (wave w covers e in [16w,16w+16))
    u64 mw = 0ull;
    const int ebase = w * 16;
#pragma unroll
    for (int ee = 0; ee < 16; ++ee) {
      const int e = ebase + ee;
      int ei = CAP - 1 - (int)(t * 64u) - e;
      float4 eb = candbox[ei];
      if (e < lane && iou_sup(eb.x, eb.y, eb.z, eb.w, carea[ei],
                              mybox.x, mybox.y, mybox.z, mybox.w, marea))
        mw |= 1ull << e;
    }
    mpart[w][lane] = mw;
    __syncthreads();
    if (w == 0) {
      u64 prior = supW[0] | supW[1] | supW[2] | supW[3];
      u64 m = mpart[0][lane] | mpart[1][lane] | mpart[2][lane] | mpart[3][lane];
      u64 remaining = __ballot(valid) & ~prior;
      u64 keptmask = 0ull;
      const int room = MAXDET - kept0;
      while (remaining != 0ull && (int)__popcll(keptmask) < room) {
        int j = __ffsll((long long)remaining) - 1;
        keptmask |= 1ull << j;
        remaining &= ~(1ull << j);
        u64 supj = __ballot(((m >> j) & 1ull) != 0ull);
        remaining &= ~supj;
      }
      if ((keptmask >> lane) & 1ull) {
        int pos = kept0 + (int)__popcll(keptmask & lmask);
        u64 mykey = keys[CAP - 1 - (int)r];
        keptbox[pos] = mybox;
        karea[pos] = marea;
        kn[pos] = (int)(~((u32)mykey));
        ksc[pos] = __uint_as_float((u32)(mykey >> 32));
      }
      if (lane == 0) s_kept = kept0 + (int)__popcll(keptmask);
    }
    __syncthreads();
  }

  const int kept = s_kept;
  for (int rr = tid; rr < MAXDET; rr += 256) {
    keptScore[bc * MAXDET + rr] = (rr < kept) ? ksc[rr] : -INFINITY;
    keptN[bc * MAXDET + rr] = (rr < kept) ? kn[rr] : 0;
  }
  if (tid == 0) {
    keptCount[bc] = kept;
    flags[bc] = (kept < MAXDET && selCount < totalC) ? 1 : 0;  // prefix exhausted
  }
}

// Exact reference-style greedy NMS for flagged problems (expected: none fire).
__global__ __launch_bounds__(256) void k_slow(const float* __restrict__ boxes,
                                              const float* __restrict__ cls,
                                              float* __restrict__ keptScore,
                                              int* __restrict__ keptN,
                                              int* __restrict__ keptCount,
                                              const int* __restrict__ flags) {
  const int bc = blockIdx.x;
  if (flags[bc] == 0) return;
  const int tid = threadIdx.x;
  const int b = bc / NCLS, c = bc % NCLS;
  const float* col = cls + (size_t)b * NBOX * NCLS + c;
  __shared__ u32 sup[(NBOX + 31) / 32];
  __shared__ u64 red[256];
  __shared__ float4 sbx;
  __shared__ int s_kept;
  for (int i = tid; i < (NBOX + 31) / 32; i += 256) sup[i] = 0u;
  if (tid == 0) s_kept = 0;
  __syncthreads();
  for (int it = 0; it < MAXDET; ++it) {
    u64 best = 0ull;
    for (int n = tid; n < NBOX; n += 256) {
      if ((sup[n >> 5] >> (n & 31)) & 1u) continue;
      float s = col[(size_t)n * NCLS];
      if (s > SCORE_THR) {
        u64 key = ((u64)__float_as_uint(s) << 32) | (~(u32)n);
        if (key > best) best = key;
      }
    }
    red[tid] = best;
    __syncthreads();
    for (int off = 128; off > 0; off >>= 1) {
      if (tid < off) { u64 o = red[tid + off]; if (o > red[tid]) red[tid] = o; }
      __syncthreads();
    }
    u64 win = red[0];
    if (win == 0ull) break;
    u32 nw = ~((u32)win);
    if (tid == 0) {
      int k = s_kept;
      keptScore[bc * MAXDET + k] = __uint_as_float((u32)(win >> 32));
      keptN[bc * MAXDET + k] = (int)nw;
      s_kept = k + 1;
      sbx = ((const float4*)boxes)[(size_t)b * NBOX + nw];
    }
    __syncthreads();
    float4 bx = sbx;
    for (int n = tid; n < NBOX; n += 256) {
      float4 cb = ((const float4*)boxes)[(size_t)b * NBOX + n];
      if (iou_gt_half(bx.x, bx.y, bx.z, bx.w, cb.x, cb.y, cb.z, cb.w))
        atomicOr(&sup[n >> 5], 1u << (n & 31));
    }
    if (tid == 0) atomicOr(&sup[nw >> 5], 1u << (nw & 31));
    __syncthreads();
  }
  __syncthreads();
  const int kept = s_kept;
  for (int r = kept + tid; r < MAXDET; r += 256) {
    keptScore[bc * MAXDET + r] = -INFINITY;
    keptN[bc * MAXDET + r] = 0;
  }
  if (tid == 0) keptCount[bc] = kept;
}

// Per-batch global top-300: 2-level histogram select + bitonic (exact lax.top_k ties).
__global__ __launch_bounds__(256) void k_out(const float* __restrict__ boxes,
                                             const float* __restrict__ rel,
                                             const float* __restrict__ keptScore,
                                             const int* __restrict__ keptN,
                                             float* __restrict__ out) {
  __shared__ __align__(16) char smem[24576];
  u32* hist = (u32*)smem;
  u64* keys = (u64*)(smem + 16384);  // [1024]
  __shared__ u32 wsum[4], selA[4], selB[4];
  __shared__ u32 s_cnt, s_sz;
  const int tid = threadIdx.x;
  const int lane = tid & 63;
  const u64 lmask = (1ull << lane) - 1ull;
  const int b = blockIdx.x;
  const int NTOT = NCLS * MAXDET;  // 24000
  const float* ks = keptScore + (size_t)b * NTOT;
  const float4* ks4 = (const float4*)ks;

  for (int i = tid; i < 4096; i += 256) hist[i] = 0u;
  if (tid == 0) s_cnt = 0u;
  __syncthreads();
  for (int base = 0; base < NTOT / 4; base += 2048) {
    float4 v[8];
#pragma unroll
    for (int p = 0; p < 8; ++p) {
      int q = base + tid + (p << 8);
      if (q < NTOT / 4) v[p] = ks4[q];
    }
#pragma unroll
    for (int p = 0; p < 8; ++p) {
      int q = base + tid + (p << 8);
      if (q < NTOT / 4) {
        float vv[4] = {v[p].x, v[p].y, v[p].z, v[p].w};
#pragma unroll
        for (int e = 0; e < 4; ++e)
          if (vv[e] > 0.0f) atomicAdd(&hist[__float_as_uint(vv[e]) >> 19], 1u);
      }
    }
  }
  __syncthreads();
  suffix_fast<4096>(hist, (u32)MAXDET, wsum, selA);
  const u32 totalC = selA[3];
  const u32 target = totalC < (u32)MAXDET ? totalC : (u32)MAXDET;

  if (totalC != 0u) {
    const u32 B0 = selA[0];
    const u32 aboveC = selA[2];
    const u32 need = target - aboveC;
    for (int i = tid; i < 4096; i += 256) hist[i] = 0u;
    __syncthreads();
    for (int base = 0; base < NTOT / 4; base += 2048) {
      float4 v[8];
#pragma unroll
      for (int p = 0; p < 8; ++p) {
        int q = base + tid + (p << 8);
        if (q < NTOT / 4) v[p] = ks4[q];
      }
#pragma unroll
      for (int p = 0; p < 8; ++p) {
        int q = base + tid + (p << 8);
        if (q < NTOT / 4) {
          float vv[4] = {v[p].x, v[p].y, v[p].z, v[p].w};
#pragma unroll
          for (int e = 0; e < 4; ++e) {
            if (vv[e] > 0.0f) {
              u32 bits = __float_as_uint(vv[e]);
              if ((bits >> 19) == B0) atomicAdd(&hist[(bits >> 7) & 0xFFFu], 1u);
            }
          }
        }
      }
    }
    __syncthreads();
    suffix_fast<4096>(hist, need, wsum, selB);
    const u32 F0 = selB[0];
    const u32 selCount = aboveC + selB[1];

    if (selCount <= 1024u) {
      for (int base = 0; base < NTOT / 4; base += 2048) {
        float4 v[8];
#pragma unroll
        for (int p = 0; p < 8; ++p) {
          int q = base + tid + (p << 8);
          if (q < NTOT / 4) v[p] = ks4[q];
        }
#pragma unroll
        for (int p = 0; p < 8; ++p) {
          int q = base + tid + (p << 8);
          if (q < NTOT / 4) {
            float vv[4] = {v[p].x, v[p].y, v[p].z, v[p].w};
#pragma unroll
            for (int e = 0; e < 4; ++e) {
              u32 bits = __float_as_uint(vv[e]);
              u32 cb = bits >> 19;
              bool sel = (vv[e] > 0.0f) &&
                         (cb > B0 || (cb == B0 && ((bits >> 7) & 0xFFFu) >= F0));
              u64 ms = __ballot(sel);
              if (ms) {
                u32 bs;
                if (lane == 0) bs = atomicAdd(&s_cnt, (u32)__popcll(ms));
                bs = __shfl(bs, 0);
                if (sel)
                  keys[bs + (u32)__popcll(ms & lmask)] =
                      ((u64)bits << 32) | (~(u32)(q * 4 + e));
              }
            }
          }
        }
      }
      const int SZ = (selCount <= 512u) ? 512 : 1024;
      if (tid == 0) s_sz = (u32)SZ;
      __syncthreads();
      for (int i = (int)selCount + tid; i < SZ; i += 256) keys[i] = 0ull;
      __syncthreads();
      bitonic_sort(keys, SZ, tid);
    } else {
      // fallback: serial 80-way merge (only on >1024-way ties)
      if (tid == 0) s_sz = 1024u;
      __syncthreads();
      if (tid < 64) {
        const int c0 = lane, c1 = 64 + lane;
        const bool has1 = (c1 < NCLS);
        const float* ls0 = keptScore + ((size_t)b * NCLS + c0) * MAXDET;
        const float* ls1 = keptScore + ((size_t)b * NCLS + (has1 ? c1 : c0)) * MAXDET;
        int h0 = 0, h1 = 0;
        float v0 = ls0[0], w0v = ls0[1];
        float v1 = has1 ? ls1[0] : -INFINITY;
        float w1v = has1 ? ls1[1] : -INFINITY;
        for (int r = 0; r < (int)target; ++r) {
          float bs; int bcl;
          if (has1 && v1 > v0) { bs = v1; bcl = c1; } else { bs = v0; bcl = c0; }
#pragma unroll
          for (int off = 32; off > 0; off >>= 1) {
            float os = __shfl_xor(bs, off);
            int oc = __shfl_xor(bcl, off);
            if (os > bs || (os == bs && oc < bcl)) { bs = os; bcl = oc; }
          }
          if (bcl == c0) {
            keys[1023 - r] = ((u64)__float_as_uint(bs) << 32) | (~(u32)(c0 * MAXDET + h0));
            ++h0; v0 = w0v; w0v = (h0 + 1 < MAXDET) ? ls0[h0 + 1] : -INFINITY;
          } else if (has1 && bcl == c1) {
            keys[1023 - r] = ((u64)__float_as_uint(bs) << 32) | (~(u32)(c1 * MAXDET + h1));
            ++h1; v1 = w1v; w1v = (h1 + 1 < MAXDET) ? ls1[h1 + 1] : -INFINITY;
          }
        }
      }
      __syncthreads();
    }
  }

  const int SZr = (totalC != 0u) ? (int)s_sz : 0;
  for (int r = tid; r < MAXDET; r += 256) {
    const bool valid = (u32)r < target;
    float s = -1.0f, pm = -1.0f, pl = -1.0f, cl = -1.0f;
    float4 ob; ob.x = ob.y = ob.z = ob.w = -1.0f;
    if (valid) {
      u64 key = keys[SZr - 1 - r];
      u32 fp = ~((u32)key);
      int c = (int)(fp / MAXDET);
      int slot = (int)(fp - (u32)c * MAXDET);
      int n = keptN[((size_t)b * NCLS + c) * MAXDET + slot];
      s = __uint_as_float((u32)(key >> 32));
      cl = (float)c;
      size_t nb = (size_t)b * NBOX + (u32)n;
      ob = ((const float4*)boxes)[nb];
      const float* rp = rel + nb * NREL;
      float best = rp[0]; int bi = 0;
      for (int p = 1; p < NREL; ++p) { float vv = rp[p]; if (vv > best) { best = vv; bi = p; } }
      pm = best; pl = (float)bi;
    }
    ((float4*)out)[(size_t)b * MAXDET + r] = ob;
    const int sbase = NBATCH * MAXDET * 4;
    out[sbase + b * MAXDET + r] = s;
    out[sbase + NBATCH * MAXDET + b * MAXDET + r] = cl;
    out[sbase + 2 * NBATCH * MAXDET + b * MAXDET + r] = pm;
    out[sbase + 3 * NBATCH * MAXDET + b * MAXDET + r] = pl;
  }
}

extern "C" void kernel_launch(void* const* d_in, const int* in_sizes, int n_in,
                              void* d_out, int out_size, void* d_ws, size_t ws_size,
                              hipStream_t stream) {
  (void)in_sizes; (void)n_in; (void)out_size;
  const float* boxes = (const float*)d_in[0];
  const float* cls   = (const float*)d_in[1];
  const float* rel   = (const float*)d_in[2];
  float* out = (float*)d_out;
  char* ws = (char*)d_ws;

  const size_t trBytes = (size_t)NBATCH * NCLS * NBOX * 4;  // 51.2 MB
  const size_t keptBytes = (size_t)NBATCH * NCLS * MAXDET * 8 + NBATCH * NCLS * 8;
  const bool useTr = ws_size >= trBytes + keptBytes;

  float* colS = (float*)ws;
  char* kbase = useTr ? (ws + trBytes) : ws;
  float* keptScore = (float*)kbase;
  int* keptN = (int*)(kbase + (size_t)NBATCH * NCLS * MAXDET * 4);
  int* keptCount = (int*)(kbase + (size_t)NBATCH * NCLS * MAXDET * 8);
  int* flags = keptCount + NBATCH * NCLS;

  if (useTr) {
    k_tr<<<dim3((NBOX + 63) / 64, NBATCH), 256, 0, stream>>>(cls, colS);
    k_nms<1><<<NBATCH * NCLS, 256, 0, stream>>>(boxes, colS, keptScore, keptN, keptCount, flags);
  } else {
    k_nms<NCLS><<<NBATCH * NCLS, 256, 0, stream>>>(boxes, cls, keptScore, keptN, keptCount, flags);
  }
  k_slow<<<NBATCH * NCLS, 256, 0, stream>>>(boxes, cls, keptScore, keptN, keptCount, flags);
  k_out<<<NBATCH, 256, 0, stream>>>(boxes, rel, keptScore, keptN, out);
}

// Round 5
// 181.224 us; speedup vs baseline: 5.3396x; 1.1158x over previous
//
#include <hip/hip_runtime.h>
#include <hip/hip_bf16.h>
#include <math.h>

#define NBATCH 8
#define NBOX   20000
#define NCLS   80
#define NREL   51
#define MAXDET 300
#define CAP    512
#define SPECCAP 2560
#define NHB    3328
#define HB0    (0x3F666666u >> 9)   // bucket base = bits(0.9f) >> 9
#define TARGETK 480u
#define SCORE_THR 0.05f
#define SPEC_THRF 0.9f

typedef unsigned long long u64;
typedef unsigned int u32;

// IoU > 0.5, bit-exact vs numpy. a = already-selected box (+ area), b = candidate.
__device__ __forceinline__ bool iou_sup(float ax1, float ay1, float ax2, float ay2, float aarea,
                                        float bx1, float by1, float bx2, float by2, float barea) {
  float ix1 = fmaxf(ax1, bx1);
  float iy1 = fmaxf(ay1, by1);
  float ix2 = fminf(ax2, bx2);
  float iy2 = fminf(ay2, by2);
  float dw = fmaxf(__fsub_rn(ix2, ix1), 0.0f);
  float dh = fmaxf(__fsub_rn(iy2, iy1), 0.0f);
  float inter = __fmul_rn(dw, dh);
  float uni = __fsub_rn(__fadd_rn(aarea, barea), inter);
  if (!(uni > 0.0f)) return false;
  return __fdiv_rn(inter, uni) > 0.5f;
}

__device__ __forceinline__ bool iou_gt_half(float ax1, float ay1, float ax2, float ay2,
                                            float bx1, float by1, float bx2, float by2) {
  float aa = __fmul_rn(__fsub_rn(ax2, ax1), __fsub_rn(ay2, ay1));
  float ab = __fmul_rn(__fsub_rn(bx2, bx1), __fsub_rn(by2, by1));
  return iou_sup(ax1, ay1, ax2, ay2, aa, bx1, by1, bx2, by2, ab);
}

#define CEXR(x, y, asc) { bool sw_ = (asc) ? ((x) > (y)) : ((x) < (y)); \
                          if (sw_) { u64 t_ = (x); (x) = (y); (y) = t_; } }

// Bitonic sort ascending over SZ u64 keys in LDS; 4 elems/thread; j<=2 passes in registers.
__device__ __forceinline__ void bitonic_sort(u64* keys, int SZ, int tid) {
  for (int k = 2; k <= SZ; k <<= 1) {
    for (int j = k >> 1; j >= 4; j >>= 1) {
      for (int v = tid; v < (SZ >> 1); v += 256) {
        int i = ((v & ~(j - 1)) << 1) | (v & (j - 1));
        int p = i | j;
        bool asc = ((i & k) == 0);
        u64 a = keys[i], b = keys[p];
        bool sw = asc ? (a > b) : (a < b);
        if (sw) { keys[i] = b; keys[p] = a; }
      }
      __syncthreads();
    }
    if (tid < (SZ >> 2)) {
      ulonglong2* k2 = (ulonglong2*)keys;
      ulonglong2 lo = k2[tid * 2], hi = k2[tid * 2 + 1];
      u64 a = lo.x, b = lo.y, c = hi.x, d = hi.y;
      int i0 = tid << 2;
      if (k == 2) {
        CEXR(a, b, true); CEXR(c, d, false);
      } else {
        bool asc = ((i0 & k) == 0);
        CEXR(a, c, asc); CEXR(b, d, asc);  // j = 2
        CEXR(a, b, asc); CEXR(c, d, asc);  // j = 1
      }
      lo.x = a; lo.y = b; hi.x = c; hi.y = d;
      k2[tid * 2] = lo; k2[tid * 2 + 1] = hi;
    }
    __syncthreads();
  }
}

// Barrier-light suffix select over NB buckets: minimal suffix >= min(total, cap).
// sout: [0]=bucket [1]=sel [2]=above [3]=total.
template <int NB>
__device__ __forceinline__ void suffix_fast(const u32* hist, u32 cap, u32* wsum4, u32* sout) {
  const int tid = threadIdx.x, lane = tid & 63, w = tid >> 6;
  const int G = NB / 256;
  u32 v = 0;
  const int hb = tid * G;
#pragma unroll
  for (int t = 0; t < G; ++t) v += hist[hb + t];
  u32 s = v;
#pragma unroll
  for (int off = 1; off < 64; off <<= 1) {
    u32 t2 = __shfl_down(s, off);
    if (lane + off < 64) s += t2;
  }
  if (lane == 0) wsum4[w] = s;
  __syncthreads();
  u32 total = wsum4[0] + wsum4[1] + wsum4[2] + wsum4[3];
  u32 after = 0;
#pragma unroll
  for (int ww = 1; ww < 4; ++ww) if (ww > w) after += wsum4[ww];
  u32 inc = s + after;
  u32 exc = inc - v;
  if (tid == 0) sout[3] = total;
  u32 target = total < cap ? total : cap;
  if (total != 0u && inc >= target && exc < target) {  // exactly one thread
    u32 acc = exc;
    for (int u = hb + G - 1; u >= hb; --u) {
      acc += hist[u];
      if (acc >= target) { sout[0] = (u32)u; sout[1] = acc; sout[2] = acc - hist[u]; break; }
    }
  }
  __syncthreads();
}

// Transpose cls (B,N,C) -> colS (B,C,N).
__global__ __launch_bounds__(256) void k_tr(const float* __restrict__ cls,
                                            float* __restrict__ colS) {
  __shared__ float tile[NCLS * 65];
  const int tid = threadIdx.x;
  const int b = blockIdx.y;
  const int n0 = blockIdx.x * 64;
  const int rows = (NBOX - n0) < 64 ? (NBOX - n0) : 64;
  const float4* src4 = (const float4*)(cls + ((size_t)b * NBOX + n0) * NCLS);
  const int nq = rows * (NCLS / 4);
  for (int i = tid; i < nq; i += 256) {
    int rr = i / (NCLS / 4);
    int c4 = i - rr * (NCLS / 4);
    float4 v = src4[i];
    tile[(c4 * 4 + 0) * 65 + rr] = v.x;
    tile[(c4 * 4 + 1) * 65 + rr] = v.y;
    tile[(c4 * 4 + 2) * 65 + rr] = v.z;
    tile[(c4 * 4 + 3) * 65 + rr] = v.w;
  }
  __syncthreads();
  float4* dst4 = (float4*)colS;
  for (int i = tid; i < NCLS * 16; i += 256) {
    int c = i >> 4, nl = i & 15;
    if (nl * 4 < rows) {
      float4 v;
      v.x = tile[c * 65 + nl * 4 + 0];
      v.y = tile[c * 65 + nl * 4 + 1];
      v.z = tile[c * 65 + nl * 4 + 2];
      v.w = tile[c * 65 + nl * 4 + 3];
      dst4[(((size_t)b * NCLS + c) * NBOX + n0) / 4 + nl] = v;
    }
  }
}

template <int STRIDE>
__device__ __forceinline__ float4 load4s(const float* col, int q) {
  if (STRIDE == 1) return ((const float4*)col)[q];
  float4 v;
  v.x = col[(size_t)(q * 4 + 0) * STRIDE];
  v.y = col[(size_t)(q * 4 + 1) * STRIDE];
  v.z = col[(size_t)(q * 4 + 2) * STRIDE];
  v.w = col[(size_t)(q * 4 + 3) * STRIDE];
  return v;
}

// Phase A: single scan + speculative (>0.9) side buffer + flat 512-ULP histogram ->
// exact top-~TARGETK selection -> bitonic sort -> sorted keys to global.
template <int STRIDE>
__global__ __launch_bounds__(256) void k_sel(const float* __restrict__ scores,
                                             u64* __restrict__ keysBase, size_t kstride,
                                             int* __restrict__ selCnt,
                                             int* __restrict__ totCnt,
                                             int* __restrict__ flags) {
  __shared__ __align__(16) char smem[SPECCAP * 8 + NHB * 4 + CAP * 8];  // 37888 B
  u64* side = (u64*)smem;
  u32* hist = (u32*)(smem + SPECCAP * 8);
  u64* keys = (u64*)(smem + SPECCAP * 8 + NHB * 4);
  __shared__ u32 wsum[4], selB[4], twave[4];
  __shared__ u32 s_scnt, s_cnt;

  const int tid = threadIdx.x;
  const int lane = tid & 63;
  const int w = tid >> 6;
  const u64 lmask = (1ull << lane) - 1ull;
  const int bc = blockIdx.x;
  const int b = bc / NCLS, c = bc % NCLS;
  const float* col = (STRIDE == 1) ? (scores + (size_t)bc * NBOX)
                                   : (scores + (size_t)b * NBOX * NCLS + c);

  for (int i = tid; i < NHB; i += 256) hist[i] = 0u;
  if (tid == 0) { s_scnt = 0u; s_cnt = 0u; }
  __syncthreads();

  // Single scan: spec (>0.9) -> side buffer + hist; tail (0.05 < s <= 0.9) counted.
  u32 tailc = 0;
  for (int base = 0; base < NBOX / 4; base += 2048) {
    float4 v[8];
#pragma unroll
    for (int p = 0; p < 8; ++p) {
      int q = base + tid + (p << 8);
      if (q < NBOX / 4) v[p] = load4s<STRIDE>(col, q);
    }
#pragma unroll
    for (int p = 0; p < 8; ++p) {
      int q = base + tid + (p << 8);
      if (q < NBOX / 4) {
        float vv[4] = {v[p].x, v[p].y, v[p].z, v[p].w};
#pragma unroll
        for (int e = 0; e < 4; ++e) {
          float s = vv[e];
          bool spec = s > SPEC_THRF;
          if (s > SCORE_THR && !spec) ++tailc;
          u64 mb = __ballot(spec);
          if (mb) {
            u32 bs;
            if (lane == 0) bs = atomicAdd(&s_scnt, (u32)__popcll(mb));
            bs = __shfl(bs, 0);
            if (spec) {
              u32 bits = __float_as_uint(s);
              u32 pos = bs + (u32)__popcll(mb & lmask);
              if (pos < SPECCAP) side[pos] = ((u64)bits << 32) | (~(u32)(q * 4 + e));
              u32 h = (bits >> 9) - HB0;
              if (h > NHB - 1) h = NHB - 1;
              atomicAdd(&hist[h], 1u);
            }
          }
        }
      }
    }
  }
  u32 tr = tailc;
#pragma unroll
  for (int off = 1; off < 64; off <<= 1) tr += __shfl_down(tr, off);
  if (lane == 0) twave[w] = tr;
  __syncthreads();

  const u32 specCount = s_scnt;
  const u32 tailSum = twave[0] + twave[1] + twave[2] + twave[3];
  const u32 totalAll = specCount + tailSum;

  if (totalAll == 0u) {
    if (tid == 0) { selCnt[bc] = 0; totCnt[bc] = 0; flags[bc] = 0; }
    return;
  }
  const u32 target = totalAll < TARGETK ? totalAll : TARGETK;
  if (specCount < target || specCount > SPECCAP) {  // speculation failed: exact slow path
    if (tid == 0) { selCnt[bc] = 0; totCnt[bc] = (int)totalAll; flags[bc] = 1; }
    return;
  }

  suffix_fast<NHB>(hist, target, wsum, selB);
  const u32 F0 = selB[0];
  const u32 selCount = selB[1];
  if (selCount > CAP) {  // tie pile-up beyond capacity
    if (tid == 0) { selCnt[bc] = 0; totCnt[bc] = (int)totalAll; flags[bc] = 1; }
    return;
  }

  // Compact side -> keys.
  const int iters = (int)((specCount + 255u) >> 8);
  for (int it2 = 0; it2 < iters; ++it2) {
    u32 idx = (u32)it2 * 256u + (u32)tid;
    bool act = idx < specCount;
    u64 key = act ? side[idx] : 0ull;
    u32 bits = (u32)(key >> 32);
    u32 h = (bits >> 9) - HB0;
    if (h > NHB - 1) h = NHB - 1;
    bool sel = act && (h >= F0);
    u64 ms = __ballot(sel);
    if (ms) {
      u32 bs;
      if (lane == 0) bs = atomicAdd(&s_cnt, (u32)__popcll(ms));
      bs = __shfl(bs, 0);
      if (sel) keys[bs + (u32)__popcll(ms & lmask)] = key;
    }
  }
  __syncthreads();
  for (int i = (int)selCount + tid; i < CAP; i += 256) keys[i] = 0ull;
  __syncthreads();

  bitonic_sort(keys, CAP, tid);

  u64* kout = keysBase + (size_t)bc * kstride;
  for (int i = tid; i < CAP; i += 256) kout[i] = keys[i];
  if (tid == 0) { selCnt[bc] = (int)selCount; totCnt[bc] = (int)totalAll; flags[bc] = 0; }
}

// Phase B: gather candidate boxes + tile-parallel greedy NMS walk.
__global__ __launch_bounds__(256) void k_walk(const float* __restrict__ boxes,
                                              const u64* __restrict__ keysBase, size_t kstride,
                                              const int* __restrict__ selCnt,
                                              const int* __restrict__ totCnt,
                                              float* __restrict__ keptScore,
                                              int* __restrict__ keptN,
                                              int* __restrict__ keptCount,
                                              int* __restrict__ flags) {
  __shared__ u64 keys[CAP];
  __shared__ float4 candbox[CAP];
  __shared__ float carea[CAP];
  __shared__ float4 keptbox[MAXDET];
  __shared__ float karea[MAXDET];
  __shared__ int kn[MAXDET];
  __shared__ float ksc[MAXDET];
  __shared__ u64 supW[4];
  __shared__ u64 mpart[4][64];
  __shared__ int s_kept;

  const int tid = threadIdx.x;
  const int lane = tid & 63;
  const int w = tid >> 6;
  const u64 lmask = (1ull << lane) - 1ull;
  const int bc = blockIdx.x;
  const int b = bc / NCLS;

  if (flags[bc] != 0) return;  // k_slow will produce this problem exactly
  const u32 selCount = (u32)selCnt[bc];
  const u32 totalAll = (u32)totCnt[bc];

  const u64* kin = keysBase + (size_t)bc * kstride;
  for (int i = tid; i < CAP; i += 256) keys[i] = kin[i];
  if (tid == 0) s_kept = 0;
  __syncthreads();

  for (int i = tid; i < (int)selCount; i += 256) {
    int pos = CAP - 1 - i;
    u32 n = ~((u32)keys[pos]);
    float4 bb = ((const float4*)boxes)[(size_t)b * NBOX + n];
    candbox[pos] = bb;
    carea[pos] = __fmul_rn(__fsub_rn(bb.z, bb.x), __fsub_rn(bb.w, bb.y));
  }
  __syncthreads();

  const u32 ntile = (selCount + 63u) >> 6;
  for (u32 t = 0; t < ntile; ++t) {
    const int kept0 = s_kept;
    if (kept0 >= MAXDET) break;
    const u32 r = t * 64u + (u32)lane;
    const bool valid = r < selCount;
    const int si = valid ? (CAP - 1 - (int)r) : (CAP - 1);
    float4 mybox = candbox[si];
    float marea = carea[si];
    // phase 1: prior-kept suppression (wave w covers kept indices w::4)
    bool sup = false;
    for (int k = w; k < kept0; k += 4) {
      float4 kb = keptbox[k];
      if (iou_sup(kb.x, kb.y, kb.z, kb.w, karea[k], mybox.x, mybox.y, mybox.z, mybox.w, marea))
        sup = true;
    }
    u64 bal = __ballot(sup);
    if (lane == 0) supW[w] = bal;
    // phase 2: in-tile pairwise mask (wave w covers e in [16w,16w+16))
    u64 mw = 0ull;
    const int ebase = w * 16;
#pragma unroll
    for (int ee = 0; ee < 16; ++ee) {
      const int e = ebase + ee;
      int ei = CAP - 1 - (int)(t * 64u) - e;
      float4 eb = candbox[ei];
      if (e < lane && iou_sup(eb.x, eb.y, eb.z, eb.w, carea[ei],
                              mybox.x, mybox.y, mybox.z, mybox.w, marea))
        mw |= 1ull << e;
    }
    mpart[w][lane] = mw;
    __syncthreads();
    if (w == 0) {
      u64 prior = supW[0] | supW[1] | supW[2] | supW[3];
      u64 m = mpart[0][lane] | mpart[1][lane] | mpart[2][lane] | mpart[3][lane];
      u64 remaining = __ballot(valid) & ~prior;
      u64 keptmask = 0ull;
      const int room = MAXDET - kept0;
      while (remaining != 0ull && (int)__popcll(keptmask) < room) {
        int j = __ffsll((long long)remaining) - 1;
        keptmask |= 1ull << j;
        remaining &= ~(1ull << j);
        u64 supj = __ballot(((m >> j) & 1ull) != 0ull);
        remaining &= ~supj;
      }
      if ((keptmask >> lane) & 1ull) {
        int pos = kept0 + (int)__popcll(keptmask & lmask);
        u64 mykey = keys[CAP - 1 - (int)r];
        keptbox[pos] = mybox;
        karea[pos] = marea;
        kn[pos] = (int)(~((u32)mykey));
        ksc[pos] = __uint_as_float((u32)(mykey >> 32));
      }
      if (lane == 0) s_kept = kept0 + (int)__popcll(keptmask);
    }
    __syncthreads();
  }

  const int kept = s_kept;
  for (int rr = tid; rr < MAXDET; rr += 256) {
    keptScore[bc * MAXDET + rr] = (rr < kept) ? ksc[rr] : -INFINITY;
    keptN[bc * MAXDET + rr] = (rr < kept) ? kn[rr] : 0;
  }
  if (tid == 0) {
    keptCount[bc] = kept;
    flags[bc] = (kept < MAXDET && selCount < totalAll) ? 1 : 0;  // prefix exhausted
  }
}

// Exact reference-style greedy NMS for flagged problems (expected: none fire).
__global__ __launch_bounds__(256) void k_slow(const float* __restrict__ boxes,
                                              const float* __restrict__ cls,
                                              float* __restrict__ keptScore,
                                              int* __restrict__ keptN,
                                              int* __restrict__ keptCount,
                                              const int* __restrict__ flags) {
  const int bc = blockIdx.x;
  if (flags[bc] != 1) return;
  const int tid = threadIdx.x;
  const int b = bc / NCLS, c = bc % NCLS;
  const float* col = cls + (size_t)b * NBOX * NCLS + c;
  __shared__ u32 sup[(NBOX + 31) / 32];
  __shared__ u64 red[256];
  __shared__ float4 sbx;
  __shared__ int s_kept;
  for (int i = tid; i < (NBOX + 31) / 32; i += 256) sup[i] = 0u;
  if (tid == 0) s_kept = 0;
  __syncthreads();
  for (int it = 0; it < MAXDET; ++it) {
    u64 best = 0ull;
    for (int n = tid; n < NBOX; n += 256) {
      if ((sup[n >> 5] >> (n & 31)) & 1u) continue;
      float s = col[(size_t)n * NCLS];
      if (s > SCORE_THR) {
        u64 key = ((u64)__float_as_uint(s) << 32) | (~(u32)n);
        if (key > best) best = key;
      }
    }
    red[tid] = best;
    __syncthreads();
    for (int off = 128; off > 0; off >>= 1) {
      if (tid < off) { u64 o = red[tid + off]; if (o > red[tid]) red[tid] = o; }
      __syncthreads();
    }
    u64 win = red[0];
    if (win == 0ull) break;
    u32 nw = ~((u32)win);
    if (tid == 0) {
      int k = s_kept;
      keptScore[bc * MAXDET + k] = __uint_as_float((u32)(win >> 32));
      keptN[bc * MAXDET + k] = (int)nw;
      s_kept = k + 1;
      sbx = ((const float4*)boxes)[(size_t)b * NBOX + nw];
    }
    __syncthreads();
    float4 bx = sbx;
    for (int n = tid; n < NBOX; n += 256) {
      float4 cb = ((const float4*)boxes)[(size_t)b * NBOX + n];
      if (iou_gt_half(bx.x, bx.y, bx.z, bx.w, cb.x, cb.y, cb.z, cb.w))
        atomicOr(&sup[n >> 5], 1u << (n & 31));
    }
    if (tid == 0) atomicOr(&sup[nw >> 5], 1u << (nw & 31));
    __syncthreads();
  }
  __syncthreads();
  const int kept = s_kept;
  for (int r = kept + tid; r < MAXDET; r += 256) {
    keptScore[bc * MAXDET + r] = -INFINITY;
    keptN[bc * MAXDET + r] = 0;
  }
  if (tid == 0) keptCount[bc] = kept;
}

// Per-batch global top-300: 2-level histogram select + bitonic (exact lax.top_k ties).
__global__ __launch_bounds__(256) void k_out(const float* __restrict__ boxes,
                                             const float* __restrict__ rel,
                                             const float* __restrict__ keptScore,
                                             const int* __restrict__ keptN,
                                             float* __restrict__ out) {
  __shared__ __align__(16) char smem[24576];
  u32* hist = (u32*)smem;
  u64* keys = (u64*)(smem + 16384);  // [1024]
  __shared__ u32 wsum[4], selA[4], selB[4];
  __shared__ u32 s_cnt, s_sz;
  const int tid = threadIdx.x;
  const int lane = tid & 63;
  const u64 lmask = (1ull << lane) - 1ull;
  const int b = blockIdx.x;
  const int NTOT = NCLS * MAXDET;  // 24000
  const float* ks = keptScore + (size_t)b * NTOT;
  const float4* ks4 = (const float4*)ks;

  for (int i = tid; i < 4096; i += 256) hist[i] = 0u;
  if (tid == 0) s_cnt = 0u;
  __syncthreads();
  for (int base = 0; base < NTOT / 4; base += 2048) {
    float4 v[8];
#pragma unroll
    for (int p = 0; p < 8; ++p) {
      int q = base + tid + (p << 8);
      if (q < NTOT / 4) v[p] = ks4[q];
    }
#pragma unroll
    for (int p = 0; p < 8; ++p) {
      int q = base + tid + (p << 8);
      if (q < NTOT / 4) {
        float vv[4] = {v[p].x, v[p].y, v[p].z, v[p].w};
#pragma unroll
        for (int e = 0; e < 4; ++e)
          if (vv[e] > 0.0f) atomicAdd(&hist[__float_as_uint(vv[e]) >> 19], 1u);
      }
    }
  }
  __syncthreads();
  suffix_fast<4096>(hist, (u32)MAXDET, wsum, selA);
  const u32 totalC = selA[3];
  const u32 target = totalC < (u32)MAXDET ? totalC : (u32)MAXDET;

  if (totalC != 0u) {
    const u32 B0 = selA[0];
    const u32 aboveC = selA[2];
    const u32 need = target - aboveC;
    for (int i = tid; i < 4096; i += 256) hist[i] = 0u;
    __syncthreads();
    for (int base = 0; base < NTOT / 4; base += 2048) {
      float4 v[8];
#pragma unroll
      for (int p = 0; p < 8; ++p) {
        int q = base + tid + (p << 8);
        if (q < NTOT / 4) v[p] = ks4[q];
      }
#pragma unroll
      for (int p = 0; p < 8; ++p) {
        int q = base + tid + (p << 8);
        if (q < NTOT / 4) {
          float vv[4] = {v[p].x, v[p].y, v[p].z, v[p].w};
#pragma unroll
          for (int e = 0; e < 4; ++e) {
            if (vv[e] > 0.0f) {
              u32 bits = __float_as_uint(vv[e]);
              if ((bits >> 19) == B0) atomicAdd(&hist[(bits >> 7) & 0xFFFu], 1u);
            }
          }
        }
      }
    }
    __syncthreads();
    suffix_fast<4096>(hist, need, wsum, selB);
    const u32 F0 = selB[0];
    const u32 selCount = aboveC + selB[1];

    if (selCount <= 1024u) {
      for (int base = 0; base < NTOT / 4; base += 2048) {
        float4 v[8];
#pragma unroll
        for (int p = 0; p < 8; ++p) {
          int q = base + tid + (p << 8);
          if (q < NTOT / 4) v[p] = ks4[q];
        }
#pragma unroll
        for (int p = 0; p < 8; ++p) {
          int q = base + tid + (p << 8);
          if (q < NTOT / 4) {
            float vv[4] = {v[p].x, v[p].y, v[p].z, v[p].w};
#pragma unroll
            for (int e = 0; e < 4; ++e) {
              u32 bits = __float_as_uint(vv[e]);
              u32 cb = bits >> 19;
              bool sel = (vv[e] > 0.0f) &&
                         (cb > B0 || (cb == B0 && ((bits >> 7) & 0xFFFu) >= F0));
              u64 ms = __ballot(sel);
              if (ms) {
                u32 bs;
                if (lane == 0) bs = atomicAdd(&s_cnt, (u32)__popcll(ms));
                bs = __shfl(bs, 0);
                if (sel)
                  keys[bs + (u32)__popcll(ms & lmask)] =
                      ((u64)bits << 32) | (~(u32)(q * 4 + e));
              }
            }
          }
        }
      }
      const int SZ = (selCount <= 512u) ? 512 : 1024;
      if (tid == 0) s_sz = (u32)SZ;
      __syncthreads();
      for (int i = (int)selCount + tid; i < SZ; i += 256) keys[i] = 0ull;
      __syncthreads();
      bitonic_sort(keys, SZ, tid);
    } else {
      // fallback: serial 80-way merge (only on >1024-way ties)
      if (tid == 0) s_sz = 1024u;
      __syncthreads();
      if (tid < 64) {
        const int c0 = lane, c1 = 64 + lane;
        const bool has1 = (c1 < NCLS);
        const float* ls0 = keptScore + ((size_t)b * NCLS + c0) * MAXDET;
        const float* ls1 = keptScore + ((size_t)b * NCLS + (has1 ? c1 : c0)) * MAXDET;
        int h0 = 0, h1 = 0;
        float v0 = ls0[0], w0v = ls0[1];
        float v1 = has1 ? ls1[0] : -INFINITY;
        float w1v = has1 ? ls1[1] : -INFINITY;
        for (int r = 0; r < (int)target; ++r) {
          float bs; int bcl;
          if (has1 && v1 > v0) { bs = v1; bcl = c1; } else { bs = v0; bcl = c0; }
#pragma unroll
          for (int off = 32; off > 0; off >>= 1) {
            float os = __shfl_xor(bs, off);
            int oc = __shfl_xor(bcl, off);
            if (os > bs || (os == bs && oc < bcl)) { bs = os; bcl = oc; }
          }
          if (bcl == c0) {
            keys[1023 - r] = ((u64)__float_as_uint(bs) << 32) | (~(u32)(c0 * MAXDET + h0));
            ++h0; v0 = w0v; w0v = (h0 + 1 < MAXDET) ? ls0[h0 + 1] : -INFINITY;
          } else if (has1 && bcl == c1) {
            keys[1023 - r] = ((u64)__float_as_uint(bs) << 32) | (~(u32)(c1 * MAXDET + h1));
            ++h1; v1 = w1v; w1v = (h1 + 1 < MAXDET) ? ls1[h1 + 1] : -INFINITY;
          }
        }
      }
      __syncthreads();
    }
  }

  const int SZr = (totalC != 0u) ? (int)s_sz : 0;
  for (int r = tid; r < MAXDET; r += 256) {
    const bool valid = (u32)r < target;
    float s = -1.0f, pm = -1.0f, pl = -1.0f, cl = -1.0f;
    float4 ob; ob.x = ob.y = ob.z = ob.w = -1.0f;
    if (valid) {
      u64 key = keys[SZr - 1 - r];
      u32 fp = ~((u32)key);
      int c = (int)(fp / MAXDET);
      int slot = (int)(fp - (u32)c * MAXDET);
      int n = keptN[((size_t)b * NCLS + c) * MAXDET + slot];
      s = __uint_as_float((u32)(key >> 32));
      cl = (float)c;
      size_t nb = (size_t)b * NBOX + (u32)n;
      ob = ((const float4*)boxes)[nb];
      const float* rp = rel + nb * NREL;
      float best = rp[0]; int bi = 0;
      for (int p = 1; p < NREL; ++p) { float vv = rp[p]; if (vv > best) { best = vv; bi = p; } }
      pm = best; pl = (float)bi;
    }
    ((float4*)out)[(size_t)b * MAXDET + r] = ob;
    const int sbase = NBATCH * MAXDET * 4;
    out[sbase + b * MAXDET + r] = s;
    out[sbase + NBATCH * MAXDET + b * MAXDET + r] = cl;
    out[sbase + 2 * NBATCH * MAXDET + b * MAXDET + r] = pm;
    out[sbase + 3 * NBATCH * MAXDET + b * MAXDET + r] = pl;
  }
}

extern "C" void kernel_launch(void* const* d_in, const int* in_sizes, int n_in,
                              void* d_out, int out_size, void* d_ws, size_t ws_size,
                              hipStream_t stream) {
  (void)in_sizes; (void)n_in; (void)out_size;
  const float* boxes = (const float*)d_in[0];
  const float* cls   = (const float*)d_in[1];
  const float* rel   = (const float*)d_in[2];
  float* out = (float*)d_out;
  char* ws = (char*)d_ws;

  const size_t trBytes = (size_t)NBATCH * NCLS * NBOX * 4;  // 51.2 MB
  const size_t NP = NBATCH * NCLS;                          // 640 problems
  const size_t keptBytes = NP * MAXDET * 8 + NP * 16;
  const bool useTr = ws_size >= trBytes + keptBytes + (size_t)NP * CAP * 8;

  float* colS = (float*)ws;
  char* kbase = useTr ? (ws + trBytes) : ws;
  float* keptScore = (float*)kbase;
  int* keptN = (int*)(kbase + NP * MAXDET * 4);
  int* keptCount = (int*)(kbase + NP * MAXDET * 8);
  int* flags = keptCount + NP;
  int* selCnt = flags + NP;
  int* totCnt = selCnt + NP;
  u64* keysSep = (u64*)(kbase + NP * MAXDET * 8 + NP * 16);

  // Keys live in each problem's own (dead-after-scan) colS column when transposed,
  // else in a separate ws region.
  u64* keysBase = useTr ? (u64*)colS : keysSep;
  const size_t kstride = useTr ? (size_t)(NBOX / 2) : (size_t)CAP;

  if (useTr) {
    k_tr<<<dim3((NBOX + 63) / 64, NBATCH), 256, 0, stream>>>(cls, colS);
    k_sel<1><<<NP, 256, 0, stream>>>(colS, keysBase, kstride, selCnt, totCnt, flags);
  } else {
    k_sel<NCLS><<<NP, 256, 0, stream>>>(cls, keysBase, kstride, selCnt, totCnt, flags);
  }
  k_walk<<<NP, 256, 0, stream>>>(boxes, keysBase, kstride, selCnt, totCnt,
                                 keptScore, keptN, keptCount, flags);
  k_slow<<<NP, 256, 0, stream>>>(boxes, cls, keptScore, keptN, keptCount, flags);
  k_out<<<NBATCH, 256, 0, stream>>>(boxes, rel, keptScore, keptN, out);
}

// Round 6
// 159.703 us; speedup vs baseline: 6.0592x; 1.1348x over previous
//
#include <hip/hip_runtime.h>
#include <hip/hip_bf16.h>
#include <math.h>

#define NBATCH 8
#define NBOX   20000
#define NCLS   80
#define NREL   51
#define MAXDET 300
#define CAP    512
#define SPECCAP 2560
#define NHB    3328
#define HB0    (0x3F666666u >> 9)   // bucket base = bits(0.9f) >> 9
#define TARGETK 480u
#define SCORE_THR 0.05f
#define SPEC_THRF 0.9f

typedef unsigned long long u64;
typedef unsigned int u32;

// IoU > 0.5, bit-exact vs numpy. a = already-selected box (+ area), b = candidate.
__device__ __forceinline__ bool iou_sup(float ax1, float ay1, float ax2, float ay2, float aarea,
                                        float bx1, float by1, float bx2, float by2, float barea) {
  float ix1 = fmaxf(ax1, bx1);
  float iy1 = fmaxf(ay1, by1);
  float ix2 = fminf(ax2, bx2);
  float iy2 = fminf(ay2, by2);
  float dw = fmaxf(__fsub_rn(ix2, ix1), 0.0f);
  float dh = fmaxf(__fsub_rn(iy2, iy1), 0.0f);
  float inter = __fmul_rn(dw, dh);
  float uni = __fsub_rn(__fadd_rn(aarea, barea), inter);
  if (!(uni > 0.0f)) return false;
  return __fdiv_rn(inter, uni) > 0.5f;
}

__device__ __forceinline__ bool iou_gt_half(float ax1, float ay1, float ax2, float ay2,
                                            float bx1, float by1, float bx2, float by2) {
  float aa = __fmul_rn(__fsub_rn(ax2, ax1), __fsub_rn(ay2, ay1));
  float ab = __fmul_rn(__fsub_rn(bx2, bx1), __fsub_rn(by2, by1));
  return iou_sup(ax1, ay1, ax2, ay2, aa, bx1, by1, bx2, by2, ab);
}

#define CEXR(x, y, asc) { bool sw_ = (asc) ? ((x) > (y)) : ((x) < (y)); \
                          if (sw_) { u64 t_ = (x); (x) = (y); (y) = t_; } }

// Bitonic sort ascending over SZ u64 keys in LDS; 4 elems/thread; j<=2 passes in registers.
__device__ __forceinline__ void bitonic_sort(u64* keys, int SZ, int tid) {
  for (int k = 2; k <= SZ; k <<= 1) {
    for (int j = k >> 1; j >= 4; j >>= 1) {
      for (int v = tid; v < (SZ >> 1); v += 256) {
        int i = ((v & ~(j - 1)) << 1) | (v & (j - 1));
        int p = i | j;
        bool asc = ((i & k) == 0);
        u64 a = keys[i], b = keys[p];
        bool sw = asc ? (a > b) : (a < b);
        if (sw) { keys[i] = b; keys[p] = a; }
      }
      __syncthreads();
    }
    if (tid < (SZ >> 2)) {
      ulonglong2* k2 = (ulonglong2*)keys;
      ulonglong2 lo = k2[tid * 2], hi = k2[tid * 2 + 1];
      u64 a = lo.x, b = lo.y, c = hi.x, d = hi.y;
      int i0 = tid << 2;
      if (k == 2) {
        CEXR(a, b, true); CEXR(c, d, false);
      } else {
        bool asc = ((i0 & k) == 0);
        CEXR(a, c, asc); CEXR(b, d, asc);  // j = 2
        CEXR(a, b, asc); CEXR(c, d, asc);  // j = 1
      }
      lo.x = a; lo.y = b; hi.x = c; hi.y = d;
      k2[tid * 2] = lo; k2[tid * 2 + 1] = hi;
    }
    __syncthreads();
  }
}

// Barrier-light suffix select over NB buckets: minimal suffix >= min(total, cap).
// sout: [0]=bucket [1]=sel [2]=above [3]=total.
template <int NB>
__device__ __forceinline__ void suffix_fast(const u32* hist, u32 cap, u32* wsum4, u32* sout) {
  const int tid = threadIdx.x, lane = tid & 63, w = tid >> 6;
  const int G = NB / 256;
  u32 v = 0;
  const int hb = tid * G;
#pragma unroll
  for (int t = 0; t < G; ++t) v += hist[hb + t];
  u32 s = v;
#pragma unroll
  for (int off = 1; off < 64; off <<= 1) {
    u32 t2 = __shfl_down(s, off);
    if (lane + off < 64) s += t2;
  }
  if (lane == 0) wsum4[w] = s;
  __syncthreads();
  u32 total = wsum4[0] + wsum4[1] + wsum4[2] + wsum4[3];
  u32 after = 0;
#pragma unroll
  for (int ww = 1; ww < 4; ++ww) if (ww > w) after += wsum4[ww];
  u32 inc = s + after;
  u32 exc = inc - v;
  if (tid == 0) sout[3] = total;
  u32 target = total < cap ? total : cap;
  if (total != 0u && inc >= target && exc < target) {  // exactly one thread
    u32 acc = exc;
    for (int u = hb + G - 1; u >= hb; --u) {
      acc += hist[u];
      if (acc >= target) { sout[0] = (u32)u; sout[1] = acc; sout[2] = acc - hist[u]; break; }
    }
  }
  __syncthreads();
}

// Transpose cls (B,N,C) -> colS (B,C,N).
__global__ __launch_bounds__(256) void k_tr(const float* __restrict__ cls,
                                            float* __restrict__ colS) {
  __shared__ float tile[NCLS * 65];
  const int tid = threadIdx.x;
  const int b = blockIdx.y;
  const int n0 = blockIdx.x * 64;
  const int rows = (NBOX - n0) < 64 ? (NBOX - n0) : 64;
  const float4* src4 = (const float4*)(cls + ((size_t)b * NBOX + n0) * NCLS);
  const int nq = rows * (NCLS / 4);
  for (int i = tid; i < nq; i += 256) {
    int rr = i / (NCLS / 4);
    int c4 = i - rr * (NCLS / 4);
    float4 v = src4[i];
    tile[(c4 * 4 + 0) * 65 + rr] = v.x;
    tile[(c4 * 4 + 1) * 65 + rr] = v.y;
    tile[(c4 * 4 + 2) * 65 + rr] = v.z;
    tile[(c4 * 4 + 3) * 65 + rr] = v.w;
  }
  __syncthreads();
  float4* dst4 = (float4*)colS;
  for (int i = tid; i < NCLS * 16; i += 256) {
    int c = i >> 4, nl = i & 15;
    if (nl * 4 < rows) {
      float4 v;
      v.x = tile[c * 65 + nl * 4 + 0];
      v.y = tile[c * 65 + nl * 4 + 1];
      v.z = tile[c * 65 + nl * 4 + 2];
      v.w = tile[c * 65 + nl * 4 + 3];
      dst4[(((size_t)b * NCLS + c) * NBOX + n0) / 4 + nl] = v;
    }
  }
}

template <int STRIDE>
__device__ __forceinline__ float4 load4s(const float* col, int q) {
  if (STRIDE == 1) return ((const float4*)col)[q];
  float4 v;
  v.x = col[(size_t)(q * 4 + 0) * STRIDE];
  v.y = col[(size_t)(q * 4 + 1) * STRIDE];
  v.z = col[(size_t)(q * 4 + 2) * STRIDE];
  v.w = col[(size_t)(q * 4 + 3) * STRIDE];
  return v;
}

// Phase A: single scan + speculative (>0.9) side buffer + flat 512-ULP histogram ->
// exact top-~TARGETK selection -> bitonic sort -> sorted keys to global.
template <int STRIDE>
__global__ __launch_bounds__(256) void k_sel(const float* __restrict__ scores,
                                             u64* __restrict__ keysBase, size_t kstride,
                                             int* __restrict__ selCnt,
                                             int* __restrict__ totCnt,
                                             int* __restrict__ flags) {
  __shared__ __align__(16) char smem[SPECCAP * 8 + NHB * 4 + CAP * 8];  // 37888 B
  u64* side = (u64*)smem;
  u32* hist = (u32*)(smem + SPECCAP * 8);
  u64* keys = (u64*)(smem + SPECCAP * 8 + NHB * 4);
  __shared__ u32 wsum[4], selB[4], twave[4];
  __shared__ u32 s_scnt, s_cnt;

  const int tid = threadIdx.x;
  const int lane = tid & 63;
  const int w = tid >> 6;
  const u64 lmask = (1ull << lane) - 1ull;
  const int bc = blockIdx.x;
  const int b = bc / NCLS, c = bc % NCLS;
  const float* col = (STRIDE == 1) ? (scores + (size_t)bc * NBOX)
                                   : (scores + (size_t)b * NBOX * NCLS + c);

  for (int i = tid; i < NHB; i += 256) hist[i] = 0u;
  if (tid == 0) { s_scnt = 0u; s_cnt = 0u; }
  __syncthreads();

  // Single scan: spec (>0.9) -> side buffer + hist; tail (0.05 < s <= 0.9) counted.
  u32 tailc = 0;
  for (int base = 0; base < NBOX / 4; base += 2048) {
    float4 v[8];
#pragma unroll
    for (int p = 0; p < 8; ++p) {
      int q = base + tid + (p << 8);
      if (q < NBOX / 4) v[p] = load4s<STRIDE>(col, q);
    }
#pragma unroll
    for (int p = 0; p < 8; ++p) {
      int q = base + tid + (p << 8);
      if (q < NBOX / 4) {
        float vv[4] = {v[p].x, v[p].y, v[p].z, v[p].w};
#pragma unroll
        for (int e = 0; e < 4; ++e) {
          float s = vv[e];
          bool spec = s > SPEC_THRF;
          if (s > SCORE_THR && !spec) ++tailc;
          u64 mb = __ballot(spec);
          if (mb) {
            u32 bs;
            if (lane == 0) bs = atomicAdd(&s_scnt, (u32)__popcll(mb));
            bs = __shfl(bs, 0);
            if (spec) {
              u32 bits = __float_as_uint(s);
              u32 pos = bs + (u32)__popcll(mb & lmask);
              if (pos < SPECCAP) side[pos] = ((u64)bits << 32) | (~(u32)(q * 4 + e));
              u32 h = (bits >> 9) - HB0;
              if (h > NHB - 1) h = NHB - 1;
              atomicAdd(&hist[h], 1u);
            }
          }
        }
      }
    }
  }
  u32 tr = tailc;
#pragma unroll
  for (int off = 1; off < 64; off <<= 1) tr += __shfl_down(tr, off);
  if (lane == 0) twave[w] = tr;
  __syncthreads();

  const u32 specCount = s_scnt;
  const u32 tailSum = twave[0] + twave[1] + twave[2] + twave[3];
  const u32 totalAll = specCount + tailSum;

  if (totalAll == 0u) {
    if (tid == 0) { selCnt[bc] = 0; totCnt[bc] = 0; flags[bc] = 0; }
    return;
  }
  const u32 target = totalAll < TARGETK ? totalAll : TARGETK;
  if (specCount < target || specCount > SPECCAP) {  // speculation failed: exact slow path
    if (tid == 0) { selCnt[bc] = 0; totCnt[bc] = (int)totalAll; flags[bc] = 1; }
    return;
  }

  suffix_fast<NHB>(hist, target, wsum, selB);
  const u32 F0 = selB[0];
  const u32 selCount = selB[1];
  if (selCount > CAP) {  // tie pile-up beyond capacity
    if (tid == 0) { selCnt[bc] = 0; totCnt[bc] = (int)totalAll; flags[bc] = 1; }
    return;
  }

  // Compact side -> keys.
  const int iters = (int)((specCount + 255u) >> 8);
  for (int it2 = 0; it2 < iters; ++it2) {
    u32 idx = (u32)it2 * 256u + (u32)tid;
    bool act = idx < specCount;
    u64 key = act ? side[idx] : 0ull;
    u32 bits = (u32)(key >> 32);
    u32 h = (bits >> 9) - HB0;
    if (h > NHB - 1) h = NHB - 1;
    bool sel = act && (h >= F0);
    u64 ms = __ballot(sel);
    if (ms) {
      u32 bs;
      if (lane == 0) bs = atomicAdd(&s_cnt, (u32)__popcll(ms));
      bs = __shfl(bs, 0);
      if (sel) keys[bs + (u32)__popcll(ms & lmask)] = key;
    }
  }
  __syncthreads();
  for (int i = (int)selCount + tid; i < CAP; i += 256) keys[i] = 0ull;
  __syncthreads();

  bitonic_sort(keys, CAP, tid);

  u64* kout = keysBase + (size_t)bc * kstride;
  for (int i = tid; i < CAP; i += 256) kout[i] = keys[i];
  if (tid == 0) { selCnt[bc] = (int)selCount; totCnt[bc] = (int)totalAll; flags[bc] = 0; }
}

// Phase B: gather candidate boxes + tile-parallel greedy NMS walk.
__global__ __launch_bounds__(256) void k_walk(const float* __restrict__ boxes,
                                              const u64* __restrict__ keysBase, size_t kstride,
                                              const int* __restrict__ selCnt,
                                              const int* __restrict__ totCnt,
                                              float* __restrict__ keptScore,
                                              int* __restrict__ keptN,
                                              int* __restrict__ keptCount,
                                              int* __restrict__ flags) {
  __shared__ u64 keys[CAP];
  __shared__ float4 candbox[CAP];
  __shared__ float carea[CAP];
  __shared__ float4 keptbox[MAXDET];
  __shared__ float karea[MAXDET];
  __shared__ int kn[MAXDET];
  __shared__ float ksc[MAXDET];
  __shared__ u64 supW[4];
  __shared__ u64 mpart[4][64];
  __shared__ int s_kept;

  const int tid = threadIdx.x;
  const int lane = tid & 63;
  const int w = tid >> 6;
  const u64 lmask = (1ull << lane) - 1ull;
  const int bc = blockIdx.x;
  const int b = bc / NCLS;

  if (flags[bc] != 0) return;  // k_slow will produce this problem exactly
  const u32 selCount = (u32)selCnt[bc];
  const u32 totalAll = (u32)totCnt[bc];

  const u64* kin = keysBase + (size_t)bc * kstride;
  for (int i = tid; i < CAP; i += 256) keys[i] = kin[i];
  if (tid == 0) s_kept = 0;
  __syncthreads();

  for (int i = tid; i < (int)selCount; i += 256) {
    int pos = CAP - 1 - i;
    u32 n = ~((u32)keys[pos]);
    float4 bb = ((const float4*)boxes)[(size_t)b * NBOX + n];
    candbox[pos] = bb;
    carea[pos] = __fmul_rn(__fsub_rn(bb.z, bb.x), __fsub_rn(bb.w, bb.y));
  }
  __syncthreads();

  const u32 ntile = (selCount + 63u) >> 6;
  for (u32 t = 0; t < ntile; ++t) {
    const int kept0 = s_kept;
    if (kept0 >= MAXDET) break;
    const u32 r = t * 64u + (u32)lane;
    const bool valid = r < selCount;
    const int si = valid ? (CAP - 1 - (int)r) : (CAP - 1);
    float4 mybox = candbox[si];
    float marea = carea[si];
    // phase 1: prior-kept suppression (wave w covers kept indices w::4)
    bool sup = false;
    for (int k = w; k < kept0; k += 4) {
      float4 kb = keptbox[k];
      if (iou_sup(kb.x, kb.y, kb.z, kb.w, karea[k], mybox.x, mybox.y, mybox.z, mybox.w, marea))
        sup = true;
    }
    u64 bal = __ballot(sup);
    if (lane == 0) supW[w] = bal;
    // phase 2: in-tile pairwise mask (wave w covers e in [16w,16w+16))
    u64 mw = 0ull;
    const int ebase = w * 16;
#pragma unroll
    for (int ee = 0; ee < 16; ++ee) {
      const int e = ebase + ee;
      int ei = CAP - 1 - (int)(t * 64u) - e;
      float4 eb = candbox[ei];
      if (e < lane && iou_sup(eb.x, eb.y, eb.z, eb.w, carea[ei],
                              mybox.x, mybox.y, mybox.z, mybox.w, marea))
        mw |= 1ull << e;
    }
    mpart[w][lane] = mw;
    __syncthreads();
    if (w == 0) {
      u64 prior = supW[0] | supW[1] | supW[2] | supW[3];
      u64 m = mpart[0][lane] | mpart[1][lane] | mpart[2][lane] | mpart[3][lane];
      u64 remaining = __ballot(valid) & ~prior;
      u64 keptmask = 0ull;
      const int room = MAXDET - kept0;
      while (remaining != 0ull && (int)__popcll(keptmask) < room) {
        int j = __ffsll((long long)remaining) - 1;
        keptmask |= 1ull << j;
        remaining &= ~(1ull << j);
        u64 supj = __ballot(((m >> j) & 1ull) != 0ull);
        remaining &= ~supj;
      }
      if ((keptmask >> lane) & 1ull) {
        int pos = kept0 + (int)__popcll(keptmask & lmask);
        u64 mykey = keys[CAP - 1 - (int)r];
        keptbox[pos] = mybox;
        karea[pos] = marea;
        kn[pos] = (int)(~((u32)mykey));
        ksc[pos] = __uint_as_float((u32)(mykey >> 32));
      }
      if (lane == 0) s_kept = kept0 + (int)__popcll(keptmask);
    }
    __syncthreads();
  }

  const int kept = s_kept;
  for (int rr = tid; rr < MAXDET; rr += 256) {
    keptScore[bc * MAXDET + rr] = (rr < kept) ? ksc[rr] : -INFINITY;
    keptN[bc * MAXDET + rr] = (rr < kept) ? kn[rr] : 0;
  }
  if (tid == 0) {
    keptCount[bc] = kept;
    flags[bc] = (kept < MAXDET && selCount < totalAll) ? 1 : 0;  // prefix exhausted
  }
}

// Exact reference-style greedy NMS for flagged problems (expected: none fire).
__global__ __launch_bounds__(256) void k_slow(const float* __restrict__ boxes,
                                              const float* __restrict__ cls,
                                              float* __restrict__ keptScore,
                                              int* __restrict__ keptN,
                                              int* __restrict__ keptCount,
                                              const int* __restrict__ flags) {
  const int bc = blockIdx.x;
  if (flags[bc] != 1) return;
  const int tid = threadIdx.x;
  const int b = bc / NCLS, c = bc % NCLS;
  const float* col = cls + (size_t)b * NBOX * NCLS + c;
  __shared__ u32 sup[(NBOX + 31) / 32];
  __shared__ u64 red[256];
  __shared__ float4 sbx;
  __shared__ int s_kept;
  for (int i = tid; i < (NBOX + 31) / 32; i += 256) sup[i] = 0u;
  if (tid == 0) s_kept = 0;
  __syncthreads();
  for (int it = 0; it < MAXDET; ++it) {
    u64 best = 0ull;
    for (int n = tid; n < NBOX; n += 256) {
      if ((sup[n >> 5] >> (n & 31)) & 1u) continue;
      float s = col[(size_t)n * NCLS];
      if (s > SCORE_THR) {
        u64 key = ((u64)__float_as_uint(s) << 32) | (~(u32)n);
        if (key > best) best = key;
      }
    }
    red[tid] = best;
    __syncthreads();
    for (int off = 128; off > 0; off >>= 1) {
      if (tid < off) { u64 o = red[tid + off]; if (o > red[tid]) red[tid] = o; }
      __syncthreads();
    }
    u64 win = red[0];
    if (win == 0ull) break;
    u32 nw = ~((u32)win);
    if (tid == 0) {
      int k = s_kept;
      keptScore[bc * MAXDET + k] = __uint_as_float((u32)(win >> 32));
      keptN[bc * MAXDET + k] = (int)nw;
      s_kept = k + 1;
      sbx = ((const float4*)boxes)[(size_t)b * NBOX + nw];
    }
    __syncthreads();
    float4 bx = sbx;
    for (int n = tid; n < NBOX; n += 256) {
      float4 cb = ((const float4*)boxes)[(size_t)b * NBOX + n];
      if (iou_gt_half(bx.x, bx.y, bx.z, bx.w, cb.x, cb.y, cb.z, cb.w))
        atomicOr(&sup[n >> 5], 1u << (n & 31));
    }
    if (tid == 0) atomicOr(&sup[nw >> 5], 1u << (nw & 31));
    __syncthreads();
  }
  __syncthreads();
  const int kept = s_kept;
  for (int r = kept + tid; r < MAXDET; r += 256) {
    keptScore[bc * MAXDET + r] = -INFINITY;
    keptN[bc * MAXDET + r] = 0;
  }
  if (tid == 0) keptCount[bc] = kept;
}

// Per-batch global top-300: single-pass flat 512-ULP histogram over (0.9,1.0] (no
// same-address atomic pile-up) + bitonic over <=512 keys (exact lax.top_k ties).
// Fallback: exact serial 80-way merge if the 300th score <= 0.9 or >512-way ties.
__global__ __launch_bounds__(256) void k_out(const float* __restrict__ boxes,
                                             const float* __restrict__ rel,
                                             const float* __restrict__ keptScore,
                                             const int* __restrict__ keptN,
                                             float* __restrict__ out) {
  __shared__ __align__(16) char smem[NHB * 4 + 1024 * 8];  // 13312 + 8192
  u32* hist = (u32*)smem;
  u64* keys = (u64*)(smem + NHB * 4);  // [1024] (merge fallback uses tail region)
  __shared__ u32 wsum[4], selB[4], twave[4];
  __shared__ u32 s_cnt, s_sz;
  const int tid = threadIdx.x;
  const int lane = tid & 63;
  const int w = tid >> 6;
  const u64 lmask = (1ull << lane) - 1ull;
  const int b = blockIdx.x;
  const int NTOT = NCLS * MAXDET;  // 24000
  const float* ks = keptScore + (size_t)b * NTOT;
  const float4* ks4 = (const float4*)ks;

  for (int i = tid; i < NHB; i += 256) hist[i] = 0u;
  if (tid == 0) s_cnt = 0u;
  __syncthreads();

  // Single pass: spec (>0.9) -> flat hist (~7/bucket, no pile-up); 0<s<=0.9 counted.
  u32 tailc = 0;
  for (int base = 0; base < NTOT / 4; base += 2048) {
    float4 v[8];
#pragma unroll
    for (int p = 0; p < 8; ++p) {
      int q = base + tid + (p << 8);
      if (q < NTOT / 4) v[p] = ks4[q];
    }
#pragma unroll
    for (int p = 0; p < 8; ++p) {
      int q = base + tid + (p << 8);
      if (q < NTOT / 4) {
        float vv[4] = {v[p].x, v[p].y, v[p].z, v[p].w};
#pragma unroll
        for (int e = 0; e < 4; ++e) {
          float s = vv[e];
          if (s > SPEC_THRF) {
            u32 h = (__float_as_uint(s) >> 9) - HB0;
            if (h > NHB - 1) h = NHB - 1;
            atomicAdd(&hist[h], 1u);
          } else if (s > 0.0f) {
            ++tailc;
          }
        }
      }
    }
  }
  u32 tr = tailc;
#pragma unroll
  for (int off = 1; off < 64; off <<= 1) tr += __shfl_down(tr, off);
  if (lane == 0) twave[w] = tr;
  __syncthreads();
  const u32 tailSum = twave[0] + twave[1] + twave[2] + twave[3];

  suffix_fast<NHB>(hist, (u32)MAXDET, wsum, selB);
  const u32 specCount = selB[3];
  const u32 totalAll = specCount + tailSum;
  const u32 target = totalAll < (u32)MAXDET ? totalAll : (u32)MAXDET;
  const u32 F0 = selB[0];
  const u32 selSpec = selB[1];

  bool fast = (totalAll != 0u) && (specCount >= target) && (selSpec <= (u32)CAP);

  if (totalAll != 0u) {
    if (fast) {
      // Compact selected (bucket >= F0) into keys, wave-aggregated.
      for (int base = 0; base < NTOT / 4; base += 2048) {
        float4 v[8];
#pragma unroll
        for (int p = 0; p < 8; ++p) {
          int q = base + tid + (p << 8);
          if (q < NTOT / 4) v[p] = ks4[q];
        }
#pragma unroll
        for (int p = 0; p < 8; ++p) {
          int q = base + tid + (p << 8);
          if (q < NTOT / 4) {
            float vv[4] = {v[p].x, v[p].y, v[p].z, v[p].w};
#pragma unroll
            for (int e = 0; e < 4; ++e) {
              float s = vv[e];
              bool sel = false;
              u32 bits = 0;
              if (s > SPEC_THRF) {
                bits = __float_as_uint(s);
                u32 h = (bits >> 9) - HB0;
                if (h > NHB - 1) h = NHB - 1;
                sel = (h >= F0);
              }
              u64 ms = __ballot(sel);
              if (ms) {
                u32 bs;
                if (lane == 0) bs = atomicAdd(&s_cnt, (u32)__popcll(ms));
                bs = __shfl(bs, 0);
                if (sel)
                  keys[bs + (u32)__popcll(ms & lmask)] =
                      ((u64)bits << 32) | (~(u32)(q * 4 + e));
              }
            }
          }
        }
      }
      if (tid == 0) s_sz = (u32)CAP;
      __syncthreads();
      for (int i = (int)selSpec + tid; i < CAP; i += 256) keys[i] = 0ull;
      __syncthreads();
      bitonic_sort(keys, CAP, tid);
    } else {
      // Exact fallback: serial 80-way merge of the sorted per-class lists.
      if (tid == 0) s_sz = 1024u;
      __syncthreads();
      if (tid < 64) {
        const int c0 = lane, c1 = 64 + lane;
        const bool has1 = (c1 < NCLS);
        const float* ls0 = keptScore + ((size_t)b * NCLS + c0) * MAXDET;
        const float* ls1 = keptScore + ((size_t)b * NCLS + (has1 ? c1 : c0)) * MAXDET;
        int h0 = 0, h1 = 0;
        float v0 = ls0[0], w0v = ls0[1];
        float v1 = has1 ? ls1[0] : -INFINITY;
        float w1v = has1 ? ls1[1] : -INFINITY;
        for (int r = 0; r < (int)target; ++r) {
          float bs; int bcl;
          if (has1 && v1 > v0) { bs = v1; bcl = c1; } else { bs = v0; bcl = c0; }
#pragma unroll
          for (int off = 32; off > 0; off >>= 1) {
            float os = __shfl_xor(bs, off);
            int oc = __shfl_xor(bcl, off);
            if (os > bs || (os == bs && oc < bcl)) { bs = os; bcl = oc; }
          }
          if (bcl == c0) {
            keys[1023 - r] = ((u64)__float_as_uint(bs) << 32) | (~(u32)(c0 * MAXDET + h0));
            ++h0; v0 = w0v; w0v = (h0 + 1 < MAXDET) ? ls0[h0 + 1] : -INFINITY;
          } else if (has1 && bcl == c1) {
            keys[1023 - r] = ((u64)__float_as_uint(bs) << 32) | (~(u32)(c1 * MAXDET + h1));
            ++h1; v1 = w1v; w1v = (h1 + 1 < MAXDET) ? ls1[h1 + 1] : -INFINITY;
          }
        }
      }
      __syncthreads();
    }
  }

  const int SZr = (totalAll != 0u) ? (int)s_sz : 0;
  for (int r = tid; r < MAXDET; r += 256) {
    const bool valid = (u32)r < target;
    float s = -1.0f, pm = -1.0f, pl = -1.0f, cl = -1.0f;
    float4 ob; ob.x = ob.y = ob.z = ob.w = -1.0f;
    if (valid) {
      u64 key = keys[SZr - 1 - r];
      u32 fp = ~((u32)key);
      int c = (int)(fp / MAXDET);
      int slot = (int)(fp - (u32)c * MAXDET);
      int n = keptN[((size_t)b * NCLS + c) * MAXDET + slot];
      s = __uint_as_float((u32)(key >> 32));
      cl = (float)c;
      size_t nb = (size_t)b * NBOX + (u32)n;
      ob = ((const float4*)boxes)[nb];
      const float* rp = rel + nb * NREL;
      float best = rp[0]; int bi = 0;
      for (int p = 1; p < NREL; ++p) { float vv = rp[p]; if (vv > best) { best = vv; bi = p; } }
      pm = best; pl = (float)bi;
    }
    ((float4*)out)[(size_t)b * MAXDET + r] = ob;
    const int sbase = NBATCH * MAXDET * 4;
    out[sbase + b * MAXDET + r] = s;
    out[sbase + NBATCH * MAXDET + b * MAXDET + r] = cl;
    out[sbase + 2 * NBATCH * MAXDET + b * MAXDET + r] = pm;
    out[sbase + 3 * NBATCH * MAXDET + b * MAXDET + r] = pl;
  }
}

extern "C" void kernel_launch(void* const* d_in, const int* in_sizes, int n_in,
                              void* d_out, int out_size, void* d_ws, size_t ws_size,
                              hipStream_t stream) {
  (void)in_sizes; (void)n_in; (void)out_size;
  const float* boxes = (const float*)d_in[0];
  const float* cls   = (const float*)d_in[1];
  const float* rel   = (const float*)d_in[2];
  float* out = (float*)d_out;
  char* ws = (char*)d_ws;

  const size_t trBytes = (size_t)NBATCH * NCLS * NBOX * 4;  // 51.2 MB
  const size_t NP = NBATCH * NCLS;                          // 640 problems
  const size_t keptBytes = NP * MAXDET * 8 + NP * 16;
  const bool useTr = ws_size >= trBytes + keptBytes + (size_t)NP * CAP * 8;

  float* colS = (float*)ws;
  char* kbase = useTr ? (ws + trBytes) : ws;
  float* keptScore = (float*)kbase;
  int* keptN = (int*)(kbase + NP * MAXDET * 4);
  int* keptCount = (int*)(kbase + NP * MAXDET * 8);
  int* flags = keptCount + NP;
  int* selCnt = flags + NP;
  int* totCnt = selCnt + NP;
  u64* keysSep = (u64*)(kbase + NP * MAXDET * 8 + NP * 16);

  // Keys live in each problem's own (dead-after-scan) colS column when transposed,
  // else in a separate ws region.
  u64* keysBase = useTr ? (u64*)colS : keysSep;
  const size_t kstride = useTr ? (size_t)(NBOX / 2) : (size_t)CAP;

  if (useTr) {
    k_tr<<<dim3((NBOX + 63) / 64, NBATCH), 256, 0, stream>>>(cls, colS);
    k_sel<1><<<NP, 256, 0, stream>>>(colS, keysBase, kstride, selCnt, totCnt, flags);
  } else {
    k_sel<NCLS><<<NP, 256, 0, stream>>>(cls, keysBase, kstride, selCnt, totCnt, flags);
  }
  k_walk<<<NP, 256, 0, stream>>>(boxes, keysBase, kstride, selCnt, totCnt,
                                 keptScore, keptN, keptCount, flags);
  k_slow<<<NP, 256, 0, stream>>>(boxes, cls, keptScore, keptN, keptCount, flags);
  k_out<<<NBATCH, 256, 0, stream>>>(boxes, rel, keptScore, keptN, out);
}

// Round 7
// 153.403 us; speedup vs baseline: 6.3080x; 1.0411x over previous
//
#include <hip/hip_runtime.h>
#include <hip/hip_bf16.h>
#include <math.h>

#define NBATCH 8
#define NBOX   20000
#define NCLS   80
#define NREL   51
#define MAXDET 300
#define CAP    512
#define SPECCAP 2560
#define NHB    3328
#define HB0    (0x3F666666u >> 9)   // bucket base = bits(0.9f) >> 9
#define TARGETK 480u
#define SCORE_THR 0.05f
#define SPEC_THRF 0.9f
#define WWAVES 8

typedef unsigned long long u64;
typedef unsigned int u32;

// IoU > 0.5, bit-exact vs numpy (explicit IEEE div). Used by k_slow only.
__device__ __forceinline__ bool iou_sup(float ax1, float ay1, float ax2, float ay2, float aarea,
                                        float bx1, float by1, float bx2, float by2, float barea) {
  float ix1 = fmaxf(ax1, bx1);
  float iy1 = fmaxf(ay1, by1);
  float ix2 = fminf(ax2, bx2);
  float iy2 = fminf(ay2, by2);
  float dw = fmaxf(__fsub_rn(ix2, ix1), 0.0f);
  float dh = fmaxf(__fsub_rn(iy2, iy1), 0.0f);
  float inter = __fmul_rn(dw, dh);
  float uni = __fsub_rn(__fadd_rn(aarea, barea), inter);
  if (!(uni > 0.0f)) return false;
  return __fdiv_rn(inter, uni) > 0.5f;
}

__device__ __forceinline__ bool iou_gt_half(float ax1, float ay1, float ax2, float ay2,
                                            float bx1, float by1, float bx2, float by2) {
  float aa = __fmul_rn(__fsub_rn(ax2, ax1), __fsub_rn(ay2, ay1));
  float ab = __fmul_rn(__fsub_rn(bx2, bx1), __fsub_rn(by2, by1));
  return iou_sup(ax1, ay1, ax2, ay2, aa, bx1, by1, bx2, by2, ab);
}

// Div-free bit-exact IoU>0.5 test:
//   rn32(inter/uni) > 0.5  ⟺  inter/uni > 0.5 + 2^-26        (ties round to even = 0.5)
//                          ⟺  2*inter > uni * (1 + 2^-25)
// Both sides exact in f64 (24-bit x 26-bit = 50-bit product < 53) -> replicates the
// IEEE f32 division+compare semantics exactly, without the ~10-inst div sequence.
__device__ __forceinline__ bool iou_sup_fast(float ax1, float ay1, float ax2, float ay2,
                                             float aarea, float bx1, float by1, float bx2,
                                             float by2, float barea) {
  float ix1 = fmaxf(ax1, bx1);
  float iy1 = fmaxf(ay1, by1);
  float ix2 = fminf(ax2, bx2);
  float iy2 = fminf(ay2, by2);
  float dw = fmaxf(__fsub_rn(ix2, ix1), 0.0f);
  float dh = fmaxf(__fsub_rn(iy2, iy1), 0.0f);
  float inter = __fmul_rn(dw, dh);
  float uni = __fsub_rn(__fadd_rn(aarea, barea), inter);
  return (uni > 0.0f) &&
         ((double)inter * 2.0 > (double)uni * 1.0000000298023223876953125);
}

#define CEXR(x, y, asc) { bool sw_ = (asc) ? ((x) > (y)) : ((x) < (y)); \
                          if (sw_) { u64 t_ = (x); (x) = (y); (y) = t_; } }

// Bitonic sort ascending over SZ u64 keys in LDS; 4 elems/thread; j<=2 passes in registers.
__device__ __forceinline__ void bitonic_sort(u64* keys, int SZ, int tid) {
  for (int k = 2; k <= SZ; k <<= 1) {
    for (int j = k >> 1; j >= 4; j >>= 1) {
      for (int v = tid; v < (SZ >> 1); v += 256) {
        int i = ((v & ~(j - 1)) << 1) | (v & (j - 1));
        int p = i | j;
        bool asc = ((i & k) == 0);
        u64 a = keys[i], b = keys[p];
        bool sw = asc ? (a > b) : (a < b);
        if (sw) { keys[i] = b; keys[p] = a; }
      }
      __syncthreads();
    }
    if (tid < (SZ >> 2)) {
      ulonglong2* k2 = (ulonglong2*)keys;
      ulonglong2 lo = k2[tid * 2], hi = k2[tid * 2 + 1];
      u64 a = lo.x, b = lo.y, c = hi.x, d = hi.y;
      int i0 = tid << 2;
      if (k == 2) {
        CEXR(a, b, true); CEXR(c, d, false);
      } else {
        bool asc = ((i0 & k) == 0);
        CEXR(a, c, asc); CEXR(b, d, asc);  // j = 2
        CEXR(a, b, asc); CEXR(c, d, asc);  // j = 1
      }
      lo.x = a; lo.y = b; hi.x = c; hi.y = d;
      k2[tid * 2] = lo; k2[tid * 2 + 1] = hi;
    }
    __syncthreads();
  }
}

// Barrier-light suffix select over NB buckets: minimal suffix >= min(total, cap).
// sout: [0]=bucket [1]=sel [2]=above [3]=total.
template <int NB>
__device__ __forceinline__ void suffix_fast(const u32* hist, u32 cap, u32* wsum4, u32* sout) {
  const int tid = threadIdx.x, lane = tid & 63, w = tid >> 6;
  const int G = NB / 256;
  u32 v = 0;
  const int hb = tid * G;
#pragma unroll
  for (int t = 0; t < G; ++t) v += hist[hb + t];
  u32 s = v;
#pragma unroll
  for (int off = 1; off < 64; off <<= 1) {
    u32 t2 = __shfl_down(s, off);
    if (lane + off < 64) s += t2;
  }
  if (lane == 0) wsum4[w] = s;
  __syncthreads();
  u32 total = wsum4[0] + wsum4[1] + wsum4[2] + wsum4[3];
  u32 after = 0;
#pragma unroll
  for (int ww = 1; ww < 4; ++ww) if (ww > w) after += wsum4[ww];
  u32 inc = s + after;
  u32 exc = inc - v;
  if (tid == 0) sout[3] = total;
  u32 target = total < cap ? total : cap;
  if (total != 0u && inc >= target && exc < target) {  // exactly one thread
    u32 acc = exc;
    for (int u = hb + G - 1; u >= hb; --u) {
      acc += hist[u];
      if (acc >= target) { sout[0] = (u32)u; sout[1] = acc; sout[2] = acc - hist[u]; break; }
    }
  }
  __syncthreads();
}

// Transpose cls (B,N,C) -> colS (B,C,N).
__global__ __launch_bounds__(256) void k_tr(const float* __restrict__ cls,
                                            float* __restrict__ colS) {
  __shared__ float tile[NCLS * 65];
  const int tid = threadIdx.x;
  const int b = blockIdx.y;
  const int n0 = blockIdx.x * 64;
  const int rows = (NBOX - n0) < 64 ? (NBOX - n0) : 64;
  const float4* src4 = (const float4*)(cls + ((size_t)b * NBOX + n0) * NCLS);
  const int nq = rows * (NCLS / 4);
  for (int i = tid; i < nq; i += 256) {
    int rr = i / (NCLS / 4);
    int c4 = i - rr * (NCLS / 4);
    float4 v = src4[i];
    tile[(c4 * 4 + 0) * 65 + rr] = v.x;
    tile[(c4 * 4 + 1) * 65 + rr] = v.y;
    tile[(c4 * 4 + 2) * 65 + rr] = v.z;
    tile[(c4 * 4 + 3) * 65 + rr] = v.w;
  }
  __syncthreads();
  float4* dst4 = (float4*)colS;
  for (int i = tid; i < NCLS * 16; i += 256) {
    int c = i >> 4, nl = i & 15;
    if (nl * 4 < rows) {
      float4 v;
      v.x = tile[c * 65 + nl * 4 + 0];
      v.y = tile[c * 65 + nl * 4 + 1];
      v.z = tile[c * 65 + nl * 4 + 2];
      v.w = tile[c * 65 + nl * 4 + 3];
      dst4[(((size_t)b * NCLS + c) * NBOX + n0) / 4 + nl] = v;
    }
  }
}

template <int STRIDE>
__device__ __forceinline__ float4 load4s(const float* col, int q) {
  if (STRIDE == 1) return ((const float4*)col)[q];
  float4 v;
  v.x = col[(size_t)(q * 4 + 0) * STRIDE];
  v.y = col[(size_t)(q * 4 + 1) * STRIDE];
  v.z = col[(size_t)(q * 4 + 2) * STRIDE];
  v.w = col[(size_t)(q * 4 + 3) * STRIDE];
  return v;
}

// Phase A: single scan + speculative (>0.9) side buffer + flat 512-ULP histogram ->
// exact top-~TARGETK selection -> bitonic sort -> sorted keys to global.
template <int STRIDE>
__global__ __launch_bounds__(256) void k_sel(const float* __restrict__ scores,
                                             u64* __restrict__ keysBase, size_t kstride,
                                             int* __restrict__ selCnt,
                                             int* __restrict__ totCnt,
                                             int* __restrict__ flags) {
  __shared__ __align__(16) char smem[SPECCAP * 8 + NHB * 4 + CAP * 8];  // 37888 B
  u64* side = (u64*)smem;
  u32* hist = (u32*)(smem + SPECCAP * 8);
  u64* keys = (u64*)(smem + SPECCAP * 8 + NHB * 4);
  __shared__ u32 wsum[4], selB[4], twave[4];
  __shared__ u32 s_scnt, s_cnt;

  const int tid = threadIdx.x;
  const int lane = tid & 63;
  const int w = tid >> 6;
  const u64 lmask = (1ull << lane) - 1ull;
  const int bc = blockIdx.x;
  const int b = bc / NCLS, c = bc % NCLS;
  const float* col = (STRIDE == 1) ? (scores + (size_t)bc * NBOX)
                                   : (scores + (size_t)b * NBOX * NCLS + c);

  for (int i = tid; i < NHB; i += 256) hist[i] = 0u;
  if (tid == 0) { s_scnt = 0u; s_cnt = 0u; }
  __syncthreads();

  // Single scan: spec (>0.9) -> side buffer + hist; tail (0.05 < s <= 0.9) counted.
  u32 tailc = 0;
  for (int base = 0; base < NBOX / 4; base += 2048) {
    float4 v[8];
#pragma unroll
    for (int p = 0; p < 8; ++p) {
      int q = base + tid + (p << 8);
      if (q < NBOX / 4) v[p] = load4s<STRIDE>(col, q);
    }
#pragma unroll
    for (int p = 0; p < 8; ++p) {
      int q = base + tid + (p << 8);
      if (q < NBOX / 4) {
        float vv[4] = {v[p].x, v[p].y, v[p].z, v[p].w};
#pragma unroll
        for (int e = 0; e < 4; ++e) {
          float s = vv[e];
          bool spec = s > SPEC_THRF;
          if (s > SCORE_THR && !spec) ++tailc;
          u64 mb = __ballot(spec);
          if (mb) {
            u32 bs;
            if (lane == 0) bs = atomicAdd(&s_scnt, (u32)__popcll(mb));
            bs = __shfl(bs, 0);
            if (spec) {
              u32 bits = __float_as_uint(s);
              u32 pos = bs + (u32)__popcll(mb & lmask);
              if (pos < SPECCAP) side[pos] = ((u64)bits << 32) | (~(u32)(q * 4 + e));
              u32 h = (bits >> 9) - HB0;
              if (h > NHB - 1) h = NHB - 1;
              atomicAdd(&hist[h], 1u);
            }
          }
        }
      }
    }
  }
  u32 tr = tailc;
#pragma unroll
  for (int off = 1; off < 64; off <<= 1) tr += __shfl_down(tr, off);
  if (lane == 0) twave[w] = tr;
  __syncthreads();

  const u32 specCount = s_scnt;
  const u32 tailSum = twave[0] + twave[1] + twave[2] + twave[3];
  const u32 totalAll = specCount + tailSum;

  if (totalAll == 0u) {
    if (tid == 0) { selCnt[bc] = 0; totCnt[bc] = 0; flags[bc] = 0; }
    return;
  }
  const u32 target = totalAll < TARGETK ? totalAll : TARGETK;
  if (specCount < target || specCount > SPECCAP) {  // speculation failed: exact slow path
    if (tid == 0) { selCnt[bc] = 0; totCnt[bc] = (int)totalAll; flags[bc] = 1; }
    return;
  }

  suffix_fast<NHB>(hist, target, wsum, selB);
  const u32 F0 = selB[0];
  const u32 selCount = selB[1];
  if (selCount > CAP) {  // tie pile-up beyond capacity
    if (tid == 0) { selCnt[bc] = 0; totCnt[bc] = (int)totalAll; flags[bc] = 1; }
    return;
  }

  // Compact side -> keys.
  const int iters = (int)((specCount + 255u) >> 8);
  for (int it2 = 0; it2 < iters; ++it2) {
    u32 idx = (u32)it2 * 256u + (u32)tid;
    bool act = idx < specCount;
    u64 key = act ? side[idx] : 0ull;
    u32 bits = (u32)(key >> 32);
    u32 h = (bits >> 9) - HB0;
    if (h > NHB - 1) h = NHB - 1;
    bool sel = act && (h >= F0);
    u64 ms = __ballot(sel);
    if (ms) {
      u32 bs;
      if (lane == 0) bs = atomicAdd(&s_cnt, (u32)__popcll(ms));
      bs = __shfl(bs, 0);
      if (sel) keys[bs + (u32)__popcll(ms & lmask)] = key;
    }
  }
  __syncthreads();
  for (int i = (int)selCount + tid; i < CAP; i += 256) keys[i] = 0ull;
  __syncthreads();

  bitonic_sort(keys, CAP, tid);

  u64* kout = keysBase + (size_t)bc * kstride;
  for (int i = tid; i < CAP; i += 256) kout[i] = keys[i];
  if (tid == 0) { selCnt[bc] = (int)selCount; totCnt[bc] = (int)totalAll; flags[bc] = 0; }
}

// Phase B: gather candidate boxes + tile-parallel greedy NMS walk.
// 8 waves cooperate: phase 1 stride-8 over kept list, phase 2 covers 8 e's/wave,
// wave 0 runs the (cheap) uniform greedy resolution. IoU test is div-free (exact).
__global__ __launch_bounds__(512) void k_walk(const float* __restrict__ boxes,
                                              const u64* __restrict__ keysBase, size_t kstride,
                                              const int* __restrict__ selCnt,
                                              const int* __restrict__ totCnt,
                                              float* __restrict__ keptScore,
                                              int* __restrict__ keptN,
                                              int* __restrict__ keptCount,
                                              int* __restrict__ flags) {
  __shared__ u64 keys[CAP];
  __shared__ float4 candbox[CAP];
  __shared__ float carea[CAP];
  __shared__ float4 keptbox[MAXDET];
  __shared__ float karea[MAXDET];
  __shared__ int kn[MAXDET];
  __shared__ float ksc[MAXDET];
  __shared__ u64 supW[WWAVES];
  __shared__ u64 mpart[WWAVES][64];
  __shared__ int s_kept;

  const int tid = threadIdx.x;
  const int lane = tid & 63;
  const int w = tid >> 6;
  const u64 lmask = (1ull << lane) - 1ull;
  const int bc = blockIdx.x;
  const int b = bc / NCLS;

  if (flags[bc] != 0) return;  // k_slow will produce this problem exactly
  const u32 selCount = (u32)selCnt[bc];
  const u32 totalAll = (u32)totCnt[bc];

  const u64* kin = keysBase + (size_t)bc * kstride;
  for (int i = tid; i < CAP; i += 512) keys[i] = kin[i];
  if (tid == 0) s_kept = 0;
  __syncthreads();

  for (int i = tid; i < (int)selCount; i += 512) {
    int pos = CAP - 1 - i;
    u32 n = ~((u32)keys[pos]);
    float4 bb = ((const float4*)boxes)[(size_t)b * NBOX + n];
    candbox[pos] = bb;
    carea[pos] = __fmul_rn(__fsub_rn(bb.z, bb.x), __fsub_rn(bb.w, bb.y));
  }
  __syncthreads();

  const u32 ntile = (selCount + 63u) >> 6;
  for (u32 t = 0; t < ntile; ++t) {
    const int kept0 = s_kept;
    if (kept0 >= MAXDET) break;
    const u32 r = t * 64u + (u32)lane;
    const bool valid = r < selCount;
    const int si = valid ? (CAP - 1 - (int)r) : (CAP - 1);
    float4 mybox = candbox[si];
    float marea = carea[si];
    // phase 1: prior-kept suppression (wave w covers kept indices w::8)
    bool sup = false;
    for (int k = w; k < kept0; k += WWAVES) {
      float4 kb = keptbox[k];
      if (iou_sup_fast(kb.x, kb.y, kb.z, kb.w, karea[k],
                       mybox.x, mybox.y, mybox.z, mybox.w, marea))
        sup = true;
    }
    u64 bal = __ballot(sup);
    if (lane == 0) supW[w] = bal;
    // phase 2: in-tile pairwise mask (wave w covers e in [8w, 8w+8))
    u64 mw = 0ull;
    const int ebase = w * 8;
#pragma unroll
    for (int ee = 0; ee < 8; ++ee) {
      const int e = ebase + ee;
      int ei = CAP - 1 - (int)(t * 64u) - e;
      float4 eb = candbox[ei];
      if (e < lane && iou_sup_fast(eb.x, eb.y, eb.z, eb.w, carea[ei],
                                   mybox.x, mybox.y, mybox.z, mybox.w, marea))
        mw |= 1ull << e;
    }
    mpart[w][lane] = mw;
    __syncthreads();
    if (w == 0) {
      u64 prior = 0ull, m = 0ull;
#pragma unroll
      for (int ww = 0; ww < WWAVES; ++ww) {
        prior |= supW[ww];
        m |= mpart[ww][lane];
      }
      u64 remaining = __ballot(valid) & ~prior;
      u64 keptmask = 0ull;
      const int room = MAXDET - kept0;
      while (remaining != 0ull && (int)__popcll(keptmask) < room) {
        int j = __ffsll((long long)remaining) - 1;
        keptmask |= 1ull << j;
        remaining &= ~(1ull << j);
        u64 supj = __ballot(((m >> j) & 1ull) != 0ull);
        remaining &= ~supj;
      }
      if ((keptmask >> lane) & 1ull) {
        int pos = kept0 + (int)__popcll(keptmask & lmask);
        u64 mykey = keys[CAP - 1 - (int)r];
        keptbox[pos] = mybox;
        karea[pos] = marea;
        kn[pos] = (int)(~((u32)mykey));
        ksc[pos] = __uint_as_float((u32)(mykey >> 32));
      }
      if (lane == 0) s_kept = kept0 + (int)__popcll(keptmask);
    }
    __syncthreads();
  }

  const int kept = s_kept;
  for (int rr = tid; rr < MAXDET; rr += 512) {
    keptScore[bc * MAXDET + rr] = (rr < kept) ? ksc[rr] : -INFINITY;
    keptN[bc * MAXDET + rr] = (rr < kept) ? kn[rr] : 0;
  }
  if (tid == 0) {
    keptCount[bc] = kept;
    flags[bc] = (kept < MAXDET && selCount < totalAll) ? 1 : 0;  // prefix exhausted
  }
}

// Exact reference-style greedy NMS for flagged problems (expected: none fire).
__global__ __launch_bounds__(256) void k_slow(const float* __restrict__ boxes,
                                              const float* __restrict__ cls,
                                              float* __restrict__ keptScore,
                                              int* __restrict__ keptN,
                                              int* __restrict__ keptCount,
                                              const int* __restrict__ flags) {
  const int bc = blockIdx.x;
  if (flags[bc] != 1) return;
  const int tid = threadIdx.x;
  const int b = bc / NCLS, c = bc % NCLS;
  const float* col = cls + (size_t)b * NBOX * NCLS + c;
  __shared__ u32 sup[(NBOX + 31) / 32];
  __shared__ u64 red[256];
  __shared__ float4 sbx;
  __shared__ int s_kept;
  for (int i = tid; i < (NBOX + 31) / 32; i += 256) sup[i] = 0u;
  if (tid == 0) s_kept = 0;
  __syncthreads();
  for (int it = 0; it < MAXDET; ++it) {
    u64 best = 0ull;
    for (int n = tid; n < NBOX; n += 256) {
      if ((sup[n >> 5] >> (n & 31)) & 1u) continue;
      float s = col[(size_t)n * NCLS];
      if (s > SCORE_THR) {
        u64 key = ((u64)__float_as_uint(s) << 32) | (~(u32)n);
        if (key > best) best = key;
      }
    }
    red[tid] = best;
    __syncthreads();
    for (int off = 128; off > 0; off >>= 1) {
      if (tid < off) { u64 o = red[tid + off]; if (o > red[tid]) red[tid] = o; }
      __syncthreads();
    }
    u64 win = red[0];
    if (win == 0ull) break;
    u32 nw = ~((u32)win);
    if (tid == 0) {
      int k = s_kept;
      keptScore[bc * MAXDET + k] = __uint_as_float((u32)(win >> 32));
      keptN[bc * MAXDET + k] = (int)nw;
      s_kept = k + 1;
      sbx = ((const float4*)boxes)[(size_t)b * NBOX + nw];
    }
    __syncthreads();
    float4 bx = sbx;
    for (int n = tid; n < NBOX; n += 256) {
      float4 cb = ((const float4*)boxes)[(size_t)b * NBOX + n];
      if (iou_gt_half(bx.x, bx.y, bx.z, bx.w, cb.x, cb.y, cb.z, cb.w))
        atomicOr(&sup[n >> 5], 1u << (n & 31));
    }
    if (tid == 0) atomicOr(&sup[nw >> 5], 1u << (nw & 31));
    __syncthreads();
  }
  __syncthreads();
  const int kept = s_kept;
  for (int r = kept + tid; r < MAXDET; r += 256) {
    keptScore[bc * MAXDET + r] = -INFINITY;
    keptN[bc * MAXDET + r] = 0;
  }
  if (tid == 0) keptCount[bc] = kept;
}

// Per-batch global top-300: single-pass flat 512-ULP histogram over (0.9,1.0] (no
// same-address atomic pile-up) + bitonic over <=512 keys (exact lax.top_k ties).
// Fallback: exact serial 80-way merge if the 300th score <= 0.9 or >512-way ties.
__global__ __launch_bounds__(256) void k_out(const float* __restrict__ boxes,
                                             const float* __restrict__ rel,
                                             const float* __restrict__ keptScore,
                                             const int* __restrict__ keptN,
                                             float* __restrict__ out) {
  __shared__ __align__(16) char smem[NHB * 4 + 1024 * 8];  // 13312 + 8192
  u32* hist = (u32*)smem;
  u64* keys = (u64*)(smem + NHB * 4);  // [1024] (merge fallback uses tail region)
  __shared__ u32 wsum[4], selB[4], twave[4];
  __shared__ u32 s_cnt, s_sz;
  const int tid = threadIdx.x;
  const int lane = tid & 63;
  const int w = tid >> 6;
  const u64 lmask = (1ull << lane) - 1ull;
  const int b = blockIdx.x;
  const int NTOT = NCLS * MAXDET;  // 24000
  const float* ks = keptScore + (size_t)b * NTOT;
  const float4* ks4 = (const float4*)ks;

  for (int i = tid; i < NHB; i += 256) hist[i] = 0u;
  if (tid == 0) s_cnt = 0u;
  __syncthreads();

  // Single pass: spec (>0.9) -> flat hist (~7/bucket, no pile-up); 0<s<=0.9 counted.
  u32 tailc = 0;
  for (int base = 0; base < NTOT / 4; base += 2048) {
    float4 v[8];
#pragma unroll
    for (int p = 0; p < 8; ++p) {
      int q = base + tid + (p << 8);
      if (q < NTOT / 4) v[p] = ks4[q];
    }
#pragma unroll
    for (int p = 0; p < 8; ++p) {
      int q = base + tid + (p << 8);
      if (q < NTOT / 4) {
        float vv[4] = {v[p].x, v[p].y, v[p].z, v[p].w};
#pragma unroll
        for (int e = 0; e < 4; ++e) {
          float s = vv[e];
          if (s > SPEC_THRF) {
            u32 h = (__float_as_uint(s) >> 9) - HB0;
            if (h > NHB - 1) h = NHB - 1;
            atomicAdd(&hist[h], 1u);
          } else if (s > 0.0f) {
            ++tailc;
          }
        }
      }
    }
  }
  u32 tr = tailc;
#pragma unroll
  for (int off = 1; off < 64; off <<= 1) tr += __shfl_down(tr, off);
  if (lane == 0) twave[w] = tr;
  __syncthreads();
  const u32 tailSum = twave[0] + twave[1] + twave[2] + twave[3];

  suffix_fast<NHB>(hist, (u32)MAXDET, wsum, selB);
  const u32 specCount = selB[3];
  const u32 totalAll = specCount + tailSum;
  const u32 target = totalAll < (u32)MAXDET ? totalAll : (u32)MAXDET;
  const u32 F0 = selB[0];
  const u32 selSpec = selB[1];

  bool fast = (totalAll != 0u) && (specCount >= target) && (selSpec <= (u32)CAP);

  if (totalAll != 0u) {
    if (fast) {
      // Compact selected (bucket >= F0) into keys, wave-aggregated.
      for (int base = 0; base < NTOT / 4; base += 2048) {
        float4 v[8];
#pragma unroll
        for (int p = 0; p < 8; ++p) {
          int q = base + tid + (p << 8);
          if (q < NTOT / 4) v[p] = ks4[q];
        }
#pragma unroll
        for (int p = 0; p < 8; ++p) {
          int q = base + tid + (p << 8);
          if (q < NTOT / 4) {
            float vv[4] = {v[p].x, v[p].y, v[p].z, v[p].w};
#pragma unroll
            for (int e = 0; e < 4; ++e) {
              float s = vv[e];
              bool sel = false;
              u32 bits = 0;
              if (s > SPEC_THRF) {
                bits = __float_as_uint(s);
                u32 h = (bits >> 9) - HB0;
                if (h > NHB - 1) h = NHB - 1;
                sel = (h >= F0);
              }
              u64 ms = __ballot(sel);
              if (ms) {
                u32 bs;
                if (lane == 0) bs = atomicAdd(&s_cnt, (u32)__popcll(ms));
                bs = __shfl(bs, 0);
                if (sel)
                  keys[bs + (u32)__popcll(ms & lmask)] =
                      ((u64)bits << 32) | (~(u32)(q * 4 + e));
              }
            }
          }
        }
      }
      if (tid == 0) s_sz = (u32)CAP;
      __syncthreads();
      for (int i = (int)selSpec + tid; i < CAP; i += 256) keys[i] = 0ull;
      __syncthreads();
      bitonic_sort(keys, CAP, tid);
    } else {
      // Exact fallback: serial 80-way merge of the sorted per-class lists.
      if (tid == 0) s_sz = 1024u;
      __syncthreads();
      if (tid < 64) {
        const int c0 = lane, c1 = 64 + lane;
        const bool has1 = (c1 < NCLS);
        const float* ls0 = keptScore + ((size_t)b * NCLS + c0) * MAXDET;
        const float* ls1 = keptScore + ((size_t)b * NCLS + (has1 ? c1 : c0)) * MAXDET;
        int h0 = 0, h1 = 0;
        float v0 = ls0[0], w0v = ls0[1];
        float v1 = has1 ? ls1[0] : -INFINITY;
        float w1v = has1 ? ls1[1] : -INFINITY;
        for (int r = 0; r < (int)target; ++r) {
          float bs; int bcl;
          if (has1 && v1 > v0) { bs = v1; bcl = c1; } else { bs = v0; bcl = c0; }
#pragma unroll
          for (int off = 32; off > 0; off >>= 1) {
            float os = __shfl_xor(bs, off);
            int oc = __shfl_xor(bcl, off);
            if (os > bs || (os == bs && oc < bcl)) { bs = os; bcl = oc; }
          }
          if (bcl == c0) {
            keys[1023 - r] = ((u64)__float_as_uint(bs) << 32) | (~(u32)(c0 * MAXDET + h0));
            ++h0; v0 = w0v; w0v = (h0 + 1 < MAXDET) ? ls0[h0 + 1] : -INFINITY;
          } else if (has1 && bcl == c1) {
            keys[1023 - r] = ((u64)__float_as_uint(bs) << 32) | (~(u32)(c1 * MAXDET + h1));
            ++h1; v1 = w1v; w1v = (h1 + 1 < MAXDET) ? ls1[h1 + 1] : -INFINITY;
          }
        }
      }
      __syncthreads();
    }
  }

  const int SZr = (totalAll != 0u) ? (int)s_sz : 0;
  for (int r = tid; r < MAXDET; r += 256) {
    const bool valid = (u32)r < target;
    float s = -1.0f, pm = -1.0f, pl = -1.0f, cl = -1.0f;
    float4 ob; ob.x = ob.y = ob.z = ob.w = -1.0f;
    if (valid) {
      u64 key = keys[SZr - 1 - r];
      u32 fp = ~((u32)key);
      int c = (int)(fp / MAXDET);
      int slot = (int)(fp - (u32)c * MAXDET);
      int n = keptN[((size_t)b * NCLS + c) * MAXDET + slot];
      s = __uint_as_float((u32)(key >> 32));
      cl = (float)c;
      size_t nb = (size_t)b * NBOX + (u32)n;
      ob = ((const float4*)boxes)[nb];
      const float* rp = rel + nb * NREL;
      float best = rp[0]; int bi = 0;
      for (int p = 1; p < NREL; ++p) { float vv = rp[p]; if (vv > best) { best = vv; bi = p; } }
      pm = best; pl = (float)bi;
    }
    ((float4*)out)[(size_t)b * MAXDET + r] = ob;
    const int sbase = NBATCH * MAXDET * 4;
    out[sbase + b * MAXDET + r] = s;
    out[sbase + NBATCH * MAXDET + b * MAXDET + r] = cl;
    out[sbase + 2 * NBATCH * MAXDET + b * MAXDET + r] = pm;
    out[sbase + 3 * NBATCH * MAXDET + b * MAXDET + r] = pl;
  }
}

extern "C" void kernel_launch(void* const* d_in, const int* in_sizes, int n_in,
                              void* d_out, int out_size, void* d_ws, size_t ws_size,
                              hipStream_t stream) {
  (void)in_sizes; (void)n_in; (void)out_size;
  const float* boxes = (const float*)d_in[0];
  const float* cls   = (const float*)d_in[1];
  const float* rel   = (const float*)d_in[2];
  float* out = (float*)d_out;
  char* ws = (char*)d_ws;

  const size_t trBytes = (size_t)NBATCH * NCLS * NBOX * 4;  // 51.2 MB
  const size_t NP = NBATCH * NCLS;                          // 640 problems
  const size_t keptBytes = NP * MAXDET * 8 + NP * 16;
  const bool useTr = ws_size >= trBytes + keptBytes + (size_t)NP * CAP * 8;

  float* colS = (float*)ws;
  char* kbase = useTr ? (ws + trBytes) : ws;
  float* keptScore = (float*)kbase;
  int* keptN = (int*)(kbase + NP * MAXDET * 4);
  int* keptCount = (int*)(kbase + NP * MAXDET * 8);
  int* flags = keptCount + NP;
  int* selCnt = flags + NP;
  int* totCnt = selCnt + NP;
  u64* keysSep = (u64*)(kbase + NP * MAXDET * 8 + NP * 16);

  // Keys live in each problem's own (dead-after-scan) colS column when transposed,
  // else in a separate ws region.
  u64* keysBase = useTr ? (u64*)colS : keysSep;
  const size_t kstride = useTr ? (size_t)(NBOX / 2) : (size_t)CAP;

  if (useTr) {
    k_tr<<<dim3((NBOX + 63) / 64, NBATCH), 256, 0, stream>>>(cls, colS);
    k_sel<1><<<NP, 256, 0, stream>>>(colS, keysBase, kstride, selCnt, totCnt, flags);
  } else {
    k_sel<NCLS><<<NP, 256, 0, stream>>>(cls, keysBase, kstride, selCnt, totCnt, flags);
  }
  k_walk<<<NP, 512, 0, stream>>>(boxes, keysBase, kstride, selCnt, totCnt,
                                 keptScore, keptN, keptCount, flags);
  k_slow<<<NP, 256, 0, stream>>>(boxes, cls, keptScore, keptN, keptCount, flags);
  k_out<<<NBATCH, 256, 0, stream>>>(boxes, rel, keptScore, keptN, out);
}